// Round 3
// baseline (1047.648 us; speedup 1.0000x reference)
//
#include <hip/hip_runtime.h>

#define NB 16
#define NA 32
#define NG 512
#define NS 1024
#define NM 8
#define NE 5
#define NOH 20
#define NFE 100
#define ND 512
#define NBINS 512
#define NTOK (NB * NS)

// ---------- block reduce (256 threads, 4 waves of 64) ----------
__device__ inline float breduce256(float v, float* s) {
#pragma unroll
  for (int off = 32; off > 0; off >>= 1) v += __shfl_down(v, off);
  __syncthreads();  // protect s from previous use
  if ((threadIdx.x & 63) == 0) s[threadIdx.x >> 6] = v;
  __syncthreads();
  return s[0] + s[1] + s[2] + s[3];
}

// ---------- 1. subset pooling + LN + thermometer formula ----------
__global__ __launch_bounds__(256) void pool_kernel(
    const float* __restrict__ vert, const float* __restrict__ mask,
    const float* __restrict__ eloh, const int* __restrict__ subs,
    const float* __restrict__ lng, const float* __restrict__ lnb,
    float* __restrict__ H, float* __restrict__ F, int tok0) {
  const int ltok = blockIdx.x;
  const int token = tok0 + ltok;
  const int b = token >> 10;  // S = 1024
  const int t = threadIdx.x;
  __shared__ float s_sub[NA];   // raw subset (float)
  __shared__ float s_w[NA];     // subs * mask^2  (pooling weight)
  __shared__ float s_counts[NE];
  __shared__ float s_red[4];
  __shared__ float s_inv[1];

  const int* srow = subs + (size_t)token * NA;
  if (t < NA) {
    float sb = (float)srow[t];
    float mk = mask[b * NA + t];
    s_sub[t] = sb;
    s_w[t] = sb * mk * mk;
  }
  __syncthreads();
  if (t == 0) {
    float z = 0.f;
    for (int a = 0; a < NA; a++) z += s_sub[a] * mask[b * NA + a];
    s_inv[0] = 1.0f / (z + 1e-4f);
  }
  if (t >= 64 && t < 64 + NE) {
    int e = t - 64;
    float c = 0.f;
    for (int a = 0; a < NA; a++) c += eloh[(size_t)(b * NA + a) * NE + e] * s_sub[a];
    s_counts[e] = c;
  }
  __syncthreads();

  const float inv = s_inv[0];
  const float* vb = vert + (size_t)b * NA * NG;
  float pm[2];
#pragma unroll
  for (int i = 0; i < 2; i++) {
    int f = t + i * 256;
    float acc = 0.f;
#pragma unroll 8
    for (int a = 0; a < NA; a++) acc += s_w[a] * vb[a * NG + f];
    pm[i] = acc * inv;
  }
  float mean = breduce256(pm[0] + pm[1], s_red) * (1.0f / NG);
  float d0 = pm[0] - mean, d1 = pm[1] - mean;
  float var = breduce256(d0 * d0 + d1 * d1, s_red) * (1.0f / NG);
  float rstd = rsqrtf(var + 1e-5f);
  float* hrow = H + (size_t)ltok * NG;
  hrow[t] = d0 * rstd * lng[t] + lnb[t];
  hrow[t + 256] = d1 * rstd * lng[t + 256] + lnb[t + 256];

  if (t < NFE) {
    int e = t / NOH, o = t % NOH;
    F[(size_t)ltok * NFE + t] = ((float)o < s_counts[e]) ? 1.0f : 0.0f;
  }
}

// ---------- 2. fp32 GEMM: C[N,Dout] = act(A[N,K] @ W[Dout,K]^T + bias) ----------
// BM=BN=128, BK=16, 256 threads, 8x8 microtile (two 4-wide sub-blocks at +0/+64)
__global__ __launch_bounds__(256) void gemm_nt(
    const float* __restrict__ A, const float* __restrict__ W,
    const float* __restrict__ bias, float* __restrict__ C,
    int K, int Dout, int act) {
  __shared__ float As[16][132];
  __shared__ float Ws[16][132];
  const int t = threadIdx.x;
  const int tx = t & 15, ty = t >> 4;
  const int bm = blockIdx.x * 128, bn = blockIdx.y * 128;
  const int lrow = t >> 1;        // 0..127
  const int lk = (t & 1) * 8;     // 0 or 8
  const float* Ag = A + (size_t)(bm + lrow) * K + lk;
  const float* Wg = W + (size_t)(bn + lrow) * K + lk;

  float acc[8][8];
#pragma unroll
  for (int i = 0; i < 8; i++)
#pragma unroll
    for (int j = 0; j < 8; j++) acc[i][j] = 0.f;

  for (int k0 = 0; k0 < K; k0 += 16) {
    if (k0 + 16 <= K) {  // fast path, aligned float4 (row strides 400B/2048B are 16B-aligned)
      float4 a0 = *(const float4*)(Ag + k0);
      float4 a1 = *(const float4*)(Ag + k0 + 4);
      float4 w0 = *(const float4*)(Wg + k0);
      float4 w1 = *(const float4*)(Wg + k0 + 4);
      As[lk + 0][lrow] = a0.x; As[lk + 1][lrow] = a0.y;
      As[lk + 2][lrow] = a0.z; As[lk + 3][lrow] = a0.w;
      As[lk + 4][lrow] = a1.x; As[lk + 5][lrow] = a1.y;
      As[lk + 6][lrow] = a1.z; As[lk + 7][lrow] = a1.w;
      Ws[lk + 0][lrow] = w0.x; Ws[lk + 1][lrow] = w0.y;
      Ws[lk + 2][lrow] = w0.z; Ws[lk + 3][lrow] = w0.w;
      Ws[lk + 4][lrow] = w1.x; Ws[lk + 5][lrow] = w1.y;
      Ws[lk + 6][lrow] = w1.z; Ws[lk + 7][lrow] = w1.w;
    } else {
#pragma unroll
      for (int j = 0; j < 8; j++) {
        int kk = k0 + lk + j;
        As[lk + j][lrow] = (kk < K) ? Ag[k0 + j] : 0.f;
        Ws[lk + j][lrow] = (kk < K) ? Wg[k0 + j] : 0.f;
      }
    }
    __syncthreads();
#pragma unroll 4
    for (int k = 0; k < 16; k++) {
      float4 a0 = *(const float4*)&As[k][ty * 4];
      float4 a1 = *(const float4*)&As[k][ty * 4 + 64];
      float4 b0 = *(const float4*)&Ws[k][tx * 4];
      float4 b1 = *(const float4*)&Ws[k][tx * 4 + 64];
      float av[8] = {a0.x, a0.y, a0.z, a0.w, a1.x, a1.y, a1.z, a1.w};
      float bv[8] = {b0.x, b0.y, b0.z, b0.w, b1.x, b1.y, b1.z, b1.w};
#pragma unroll
      for (int i = 0; i < 8; i++)
#pragma unroll
        for (int j = 0; j < 8; j++) acc[i][j] = fmaf(av[i], bv[j], acc[i][j]);
    }
    __syncthreads();
  }

  float4 bias0 = *(const float4*)&bias[bn + tx * 4];
  float4 bias1 = *(const float4*)&bias[bn + 64 + tx * 4];
  const float bb0[4] = {bias0.x, bias0.y, bias0.z, bias0.w};
  const float bb1[4] = {bias1.x, bias1.y, bias1.z, bias1.w};
#pragma unroll
  for (int i = 0; i < 8; i++) {
    int row = bm + ((i < 4) ? (ty * 4 + i) : (60 + ty * 4 + i));
    float4 v0, v1;
    float tmp0[4], tmp1[4];
#pragma unroll
    for (int j = 0; j < 4; j++) {
      float u0 = acc[i][j] + bb0[j];
      float u1 = acc[i][j + 4] + bb1[j];
      if (act) { u0 = fmaxf(u0, 0.f); u1 = fmaxf(u1, 0.f); }
      tmp0[j] = u0; tmp1[j] = u1;
    }
    v0.x = tmp0[0]; v0.y = tmp0[1]; v0.z = tmp0[2]; v0.w = tmp0[3];
    v1.x = tmp1[0]; v1.y = tmp1[1]; v1.z = tmp1[2]; v1.w = tmp1[3];
    float* crow = C + (size_t)row * Dout + bn;
    *(float4*)&crow[tx * 4] = v0;
    *(float4*)&crow[64 + tx * 4] = v1;
  }
}

// ---------- 3. GRU gates + post-LN ----------
__global__ __launch_bounds__(256) void gate_ln_kernel(
    const float* __restrict__ Gi, const float* __restrict__ Gh,
    const float* __restrict__ H, const float* __restrict__ lng,
    const float* __restrict__ lnb, float* __restrict__ X0) {
  const int token = blockIdx.x;
  const int t = threadIdx.x;
  __shared__ float s_red[4];
  const float* gi = Gi + (size_t)token * 1536;
  const float* gh = Gh + (size_t)token * 1536;
  const float* h = H + (size_t)token * NG;
  float c[2];
#pragma unroll
  for (int i = 0; i < 2; i++) {
    int f = t + i * 256;
    float r = 1.f / (1.f + expf(-(gi[f] + gh[f])));
    float z = 1.f / (1.f + expf(-(gi[NG + f] + gh[NG + f])));
    float n = tanhf(gi[2 * NG + f] + r * gh[2 * NG + f]);
    c[i] = (1.f - z) * n + z * h[f];
  }
  float mean = breduce256(c[0] + c[1], s_red) * (1.0f / NG);
  float d0 = c[0] - mean, d1 = c[1] - mean;
  float var = breduce256(d0 * d0 + d1 * d1, s_red) * (1.0f / NG);
  float rstd = rsqrtf(var + 1e-5f);
  float* x = X0 + (size_t)token * NG;
  x[t] = d0 * rstd * lng[t] + lnb[t];
  x[t + 256] = d1 * rstd * lng[t + 256] + lnb[t + 256];
}

// ---------- 4. final LN + score ----------
__global__ __launch_bounds__(256) void ln_score_kernel(
    const float* __restrict__ X, const float* __restrict__ lng,
    const float* __restrict__ lnb, const float* __restrict__ Wsc,
    const float* __restrict__ bsc, float* __restrict__ scores) {
  const int token = blockIdx.x;
  const int t = threadIdx.x;
  __shared__ float s_red[4];
  const float* x = X + (size_t)token * ND;
  float v0 = x[t], v1 = x[t + 256];
  float mean = breduce256(v0 + v1, s_red) * (1.0f / ND);
  float d0 = v0 - mean, d1 = v1 - mean;
  float var = breduce256(d0 * d0 + d1 * d1, s_red) * (1.0f / ND);
  float rstd = rsqrtf(var + 1e-5f);
  float y0 = d0 * rstd * lng[t] + lnb[t];
  float y1 = d1 * rstd * lng[t + 256] + lnb[t + 256];
  float dot = breduce256(y0 * Wsc[t] + y1 * Wsc[t + 256], s_red);
  if (t == 0) scores[token] = dot + bsc[0];
}

// ---------- 5. softmax over S per batch ----------
__global__ __launch_bounds__(256) void softmax_kernel(
    const float* __restrict__ scores, float* __restrict__ probs) {
  const int b = blockIdx.x;
  const int t = threadIdx.x;
  __shared__ float s_red[4];
  const float* sc = scores + (size_t)b * NS;
  float v[4];
  float mx = -1e30f;
#pragma unroll
  for (int i = 0; i < 4; i++) { v[i] = sc[t + i * 256]; mx = fmaxf(mx, v[i]); }
#pragma unroll
  for (int off = 32; off > 0; off >>= 1) mx = fmaxf(mx, __shfl_down(mx, off));
  if ((t & 63) == 0) s_red[t >> 6] = mx;
  __syncthreads();
  mx = fmaxf(fmaxf(s_red[0], s_red[1]), fmaxf(s_red[2], s_red[3]));
  float e[4], sum = 0.f;
#pragma unroll
  for (int i = 0; i < 4; i++) { e[i] = expf(v[i] - mx); sum += e[i]; }
  sum = breduce256(sum, s_red);
  float inv = 1.f / sum;
#pragma unroll
  for (int i = 0; i < 4; i++) probs[(size_t)b * NS + t + i * 256] = e[i] * inv;
}

// ---------- 6. sparse scatter into spectrum ----------
__global__ __launch_bounds__(256) void scatter_kernel(
    const float* __restrict__ probs, const int* __restrict__ pidx,
    const float* __restrict__ pint, float* __restrict__ spect) {
  int token = blockIdx.x * 256 + threadIdx.x;
  int b = token >> 10;
  float p = probs[token];
  const int* idx = pidx + (size_t)token * NM;
  const float* wt = pint + (size_t)token * NM;
#pragma unroll
  for (int m = 0; m < NM; m++)
    atomicAdd(&spect[b * NBINS + idx[m]], wt[m] * p);
}

extern "C" void kernel_launch(void* const* d_in, const int* in_sizes, int n_in,
                              void* d_out, int out_size, void* d_ws, size_t ws_size,
                              hipStream_t stream) {
  const float* vert = (const float*)d_in[0];
  const float* mask = (const float*)d_in[1];
  const float* eloh = (const float*)d_in[2];
  const int* subs = (const int*)d_in[3];
  const int* pidx = (const int*)d_in[4];
  const float* pint = (const float*)d_in[5];
  const float* ln_sub_g = (const float*)d_in[6];
  const float* ln_sub_b = (const float*)d_in[7];
  const float* W_ih = (const float*)d_in[8];
  const float* W_hh = (const float*)d_in[9];
  const float* b_ih = (const float*)d_in[10];
  const float* b_hh = (const float*)d_in[11];
  const float* ln_post_g = (const float*)d_in[12];
  const float* ln_post_b = (const float*)d_in[13];
  const float* W1 = (const float*)d_in[14];
  const float* b1 = (const float*)d_in[15];
  const float* W2a = (const float*)d_in[16];
  const float* b2a = (const float*)d_in[17];
  const float* W2b = (const float*)d_in[18];
  const float* b2b = (const float*)d_in[19];
  const float* ln_pre_g = (const float*)d_in[20];
  const float* ln_pre_b = (const float*)d_in[21];
  const float* W_s = (const float*)d_in[22];
  const float* b_s = (const float*)d_in[23];

  float* out = (float*)d_out;            // [0,8192) spect, [8192,24576) probs
  float* probs = out + NB * NBINS;

  // ---- ws_size-adaptive token chunking (per-token bytes = 16784) ----
  // layout: scores (64KB) | H (T*512) | F (T*100) | Gi (T*1536) | Gh (T*1536) | X0 (T*512)
  const size_t per_tok = (size_t)(NG + NFE + 3 * NG + 3 * NG + NG) * sizeof(float); // 16784
  int T = NTOK;
  while (T > 1024 && 65536 + (size_t)T * per_tok > ws_size) T >>= 1;
  const int nchunks = NTOK / T;

  float* scores = (float*)d_ws;                 // 16384 floats (64 KB incl. pad)
  float* base = scores + 16384;
  float* H  = base;
  float* F  = H + (size_t)T * NG;
  float* Gi = F + (size_t)T * NFE;
  float* Gh = Gi + (size_t)T * 3 * NG;
  float* X0 = Gh + (size_t)T * 3 * NG;
  float* X1 = Gi;      // Gi dead after gate kernel
  float* X2 = Gh;      // Gh dead after gate kernel
  float* X3 = H;       // H dead after gate kernel

  hipMemsetAsync(d_out, 0, NB * NBINS * sizeof(float), stream);

  for (int c = 0; c < nchunks; c++) {
    const int tok0 = c * T;
    pool_kernel<<<T, 256, 0, stream>>>(vert, mask, eloh, subs, ln_sub_g, ln_sub_b, H, F, tok0);

    dim3 g1(T / 128, 1536 / 128);
    gemm_nt<<<g1, 256, 0, stream>>>(F, W_ih, b_ih, Gi, NFE, 1536, 0);
    gemm_nt<<<g1, 256, 0, stream>>>(H, W_hh, b_hh, Gh, NG, 1536, 0);

    gate_ln_kernel<<<T, 256, 0, stream>>>(Gi, Gh, H, ln_post_g, ln_post_b, X0);

    dim3 g2(T / 128, ND / 128);
    gemm_nt<<<g2, 256, 0, stream>>>(X0, W1, b1, X1, NG, ND, 1);
    gemm_nt<<<g2, 256, 0, stream>>>(X1, W2a, b2a, X2, ND, ND, 1);
    gemm_nt<<<g2, 256, 0, stream>>>(X2, W2b, b2b, X3, ND, ND, 1);

    ln_score_kernel<<<T, 256, 0, stream>>>(X3, ln_pre_g, ln_pre_b, W_s, b_s, scores + tok0);
  }

  softmax_kernel<<<NB, 256, 0, stream>>>(scores, probs);
  scatter_kernel<<<NTOK / 256, 256, 0, stream>>>(probs, pidx, pint, out);
}

// Round 4
// 345.994 us; speedup vs baseline: 3.0279x; 3.0279x over previous
//
#include <hip/hip_runtime.h>

#define NB 16
#define NA 32
#define NG 512
#define NS 1024
#define NM 8
#define NE 5
#define NOH 20
#define NFE 100
#define NFEP 128   // padded formula width for K%32==0
#define ND 512
#define NBINS 512
#define NTOK (NB * NS)

typedef unsigned short ushort_t;
typedef __attribute__((ext_vector_type(8))) short bf16x8;
typedef __attribute__((ext_vector_type(4))) float f32x4;

__device__ __forceinline__ ushort_t f2bf(float x) {
  union { float f; unsigned u; } v; v.f = x;
  unsigned r = v.u + 0x7FFF + ((v.u >> 16) & 1);   // RNE
  return (ushort_t)(r >> 16);
}
__device__ __forceinline__ float bf2f(ushort_t b) {
  union { unsigned u; float f; } v; v.u = ((unsigned)b) << 16;
  return v.f;
}

__device__ __forceinline__ void gload_lds16(const void* g, void* l) {
  __builtin_amdgcn_global_load_lds(
      (const __attribute__((address_space(1))) void*)g,
      (__attribute__((address_space(3))) void*)l, 16, 0, 0);
}

// ---------- block reduce (256 threads, 4 waves of 64) ----------
__device__ inline float breduce256(float v, float* s) {
#pragma unroll
  for (int off = 32; off > 0; off >>= 1) v += __shfl_down(v, off);
  __syncthreads();
  if ((threadIdx.x & 63) == 0) s[threadIdx.x >> 6] = v;
  __syncthreads();
  return s[0] + s[1] + s[2] + s[3];
}

// ---------- weight conversion ----------
__global__ __launch_bounds__(256) void cvt_bf16_kernel(
    const float* __restrict__ src, ushort_t* __restrict__ dst, int n) {
  int i = blockIdx.x * 256 + threadIdx.x;
  if (i < n) dst[i] = f2bf(src[i]);
}
// W_ih [1536,100] -> [1536,128] zero-padded
__global__ __launch_bounds__(256) void cvt_wih_kernel(
    const float* __restrict__ src, ushort_t* __restrict__ dst) {
  int i = blockIdx.x * 256 + threadIdx.x;   // 1536*128
  int r = i >> 7, c = i & 127;
  dst[i] = (c < NFE) ? f2bf(src[r * NFE + c]) : (ushort_t)0;
}

// ---------- 1. subset pooling + LN + thermometer formula ----------
__global__ __launch_bounds__(256) void pool_kernel(
    const float* __restrict__ vert, const float* __restrict__ mask,
    const float* __restrict__ eloh, const int* __restrict__ subs,
    const float* __restrict__ lng, const float* __restrict__ lnb,
    float* __restrict__ Hf, ushort_t* __restrict__ Hb,
    ushort_t* __restrict__ F, int tok0) {
  const int ltok = blockIdx.x;
  const int token = tok0 + ltok;
  const int b = token >> 10;  // S = 1024
  const int t = threadIdx.x;
  __shared__ float s_sub[NA];
  __shared__ float s_w[NA];
  __shared__ float s_counts[NE];
  __shared__ float s_red[4];
  __shared__ float s_inv[1];

  const int* srow = subs + (size_t)token * NA;
  if (t < NA) {
    float sb = (float)srow[t];
    float mk = mask[b * NA + t];
    s_sub[t] = sb;
    s_w[t] = sb * mk * mk;
  }
  __syncthreads();
  if (t == 0) {
    float z = 0.f;
    for (int a = 0; a < NA; a++) z += s_sub[a] * mask[b * NA + a];
    s_inv[0] = 1.0f / (z + 1e-4f);
  }
  if (t >= 64 && t < 64 + NE) {
    int e = t - 64;
    float c = 0.f;
    for (int a = 0; a < NA; a++) c += eloh[(size_t)(b * NA + a) * NE + e] * s_sub[a];
    s_counts[e] = c;
  }
  __syncthreads();

  const float inv = s_inv[0];
  const float* vb = vert + (size_t)b * NA * NG;
  float pm[2];
#pragma unroll
  for (int i = 0; i < 2; i++) {
    int f = t + i * 256;
    float acc = 0.f;
#pragma unroll 8
    for (int a = 0; a < NA; a++) acc += s_w[a] * vb[a * NG + f];
    pm[i] = acc * inv;
  }
  float mean = breduce256(pm[0] + pm[1], s_red) * (1.0f / NG);
  float d0 = pm[0] - mean, d1 = pm[1] - mean;
  float var = breduce256(d0 * d0 + d1 * d1, s_red) * (1.0f / NG);
  float rstd = rsqrtf(var + 1e-5f);
  float h0 = d0 * rstd * lng[t] + lnb[t];
  float h1 = d1 * rstd * lng[t + 256] + lnb[t + 256];
  float* hf = Hf + (size_t)ltok * NG;
  ushort_t* hb = Hb + (size_t)ltok * NG;
  hf[t] = h0; hf[t + 256] = h1;
  hb[t] = f2bf(h0); hb[t + 256] = f2bf(h1);

  if (t < NFEP) {
    float v = 0.f;
    if (t < NFE) {
      int e = t / NOH, o = t % NOH;
      v = ((float)o < s_counts[e]) ? 1.0f : 0.0f;
    }
    F[(size_t)ltok * NFEP + t] = f2bf(v);
  }
}

// ---------- 2. bf16 MFMA GEMM: C[M,Dout] = act(A[M,K] @ W[Dout,K]^T + bias) ----------
// BM=BN=128, BK=32, 256 threads (4 waves, 2x2 wave grid, each wave 64x64 = 4x4 frags)
// mode: 0 = f32 out no act, 1 = bf16 out relu, 2 = f32 out relu, 3 = bf16 out no act
__global__ __launch_bounds__(256) void gemm_bf16(
    const ushort_t* __restrict__ A, const ushort_t* __restrict__ W,
    const float* __restrict__ bias, void* __restrict__ C,
    int K, int Dout, int mode) {
  __shared__ ushort_t As[128 * 32];
  __shared__ ushort_t Bs[128 * 32];
  const int t = threadIdx.x;
  const int w = t >> 6;            // wave 0..3
  const int lane = t & 63;
  const int wr = w >> 1, wc = w & 1;
  const int bm = blockIdx.x * 128, bn = blockIdx.y * 128;

  // staging: issue i covers tile rows (i*4+w)*16 .. +16 ; lane l -> row +(l>>2), colchunk (l&3)*8
  const int srow = lane >> 2;
  const int scol = (lane & 3) * 8;
  const ushort_t* Ag0 = A + (size_t)(bm + (0 * 4 + w) * 16 + srow) * K + scol;
  const ushort_t* Ag1 = A + (size_t)(bm + (1 * 4 + w) * 16 + srow) * K + scol;
  const ushort_t* Wg0 = W + (size_t)(bn + (0 * 4 + w) * 16 + srow) * K + scol;
  const ushort_t* Wg1 = W + (size_t)(bn + (1 * 4 + w) * 16 + srow) * K + scol;
  ushort_t* ldsA0 = &As[(0 * 4 + w) * 512];
  ushort_t* ldsA1 = &As[(1 * 4 + w) * 512];
  ushort_t* ldsB0 = &Bs[(0 * 4 + w) * 512];
  ushort_t* ldsB1 = &Bs[(1 * 4 + w) * 512];

  // fragment read offsets: row = frag_rowbase + (lane&15), kchunk = (lane>>4)*8
  const int lr = lane & 15;
  const int lq = lane >> 4;

  f32x4 acc[4][4];
#pragma unroll
  for (int m = 0; m < 4; m++)
#pragma unroll
    for (int n = 0; n < 4; n++) acc[m][n] = (f32x4)0.f;

  for (int k0 = 0; k0 < K; k0 += 32) {
    gload_lds16(Ag0 + k0, ldsA0);
    gload_lds16(Ag1 + k0, ldsA1);
    gload_lds16(Wg0 + k0, ldsB0);
    gload_lds16(Wg1 + k0, ldsB1);
    __syncthreads();
    bf16x8 a[4], b[4];
#pragma unroll
    for (int m = 0; m < 4; m++)
      a[m] = *(const bf16x8*)&As[(wr * 64 + m * 16 + lr) * 32 + lq * 8];
#pragma unroll
    for (int n = 0; n < 4; n++)
      b[n] = *(const bf16x8*)&Bs[(wc * 64 + n * 16 + lr) * 32 + lq * 8];
#pragma unroll
    for (int m = 0; m < 4; m++)
#pragma unroll
      for (int n = 0; n < 4; n++)
        acc[m][n] = __builtin_amdgcn_mfma_f32_16x16x32_bf16(a[m], b[n], acc[m][n], 0, 0, 0);
    __syncthreads();
  }

  // epilogue: C/D layout col = lane&15, row = (lane>>4)*4 + r
  float* Cf = (float*)C;
  ushort_t* Cb = (ushort_t*)C;
#pragma unroll
  for (int n = 0; n < 4; n++) {
    const int col = bn + wc * 64 + n * 16 + lr;
    const float bv = bias[col];
#pragma unroll
    for (int m = 0; m < 4; m++) {
      f32x4 v = acc[m][n];
#pragma unroll
      for (int r = 0; r < 4; r++) {
        int row = bm + wr * 64 + m * 16 + lq * 4 + r;
        float u = v[r] + bv;
        if (mode == 1 || mode == 2) u = fmaxf(u, 0.f);
        if (mode == 0 || mode == 2) Cf[(size_t)row * Dout + col] = u;
        else Cb[(size_t)row * Dout + col] = f2bf(u);
      }
    }
  }
}

// ---------- 3. GRU gates + post-LN (bf16 in, bf16 out) ----------
__global__ __launch_bounds__(256) void gate_ln_kernel(
    const ushort_t* __restrict__ Gi, const ushort_t* __restrict__ Gh,
    const float* __restrict__ H, const float* __restrict__ lng,
    const float* __restrict__ lnb, ushort_t* __restrict__ X0) {
  const int token = blockIdx.x;
  const int t = threadIdx.x;
  __shared__ float s_red[4];
  const ushort_t* gi = Gi + (size_t)token * 1536;
  const ushort_t* gh = Gh + (size_t)token * 1536;
  const float* h = H + (size_t)token * NG;
  float c[2];
#pragma unroll
  for (int i = 0; i < 2; i++) {
    int f = t + i * 256;
    float r = 1.f / (1.f + expf(-(bf2f(gi[f]) + bf2f(gh[f]))));
    float z = 1.f / (1.f + expf(-(bf2f(gi[NG + f]) + bf2f(gh[NG + f]))));
    float n = tanhf(bf2f(gi[2 * NG + f]) + r * bf2f(gh[2 * NG + f]));
    c[i] = (1.f - z) * n + z * h[f];
  }
  float mean = breduce256(c[0] + c[1], s_red) * (1.0f / NG);
  float d0 = c[0] - mean, d1 = c[1] - mean;
  float var = breduce256(d0 * d0 + d1 * d1, s_red) * (1.0f / NG);
  float rstd = rsqrtf(var + 1e-5f);
  ushort_t* x = X0 + (size_t)token * NG;
  x[t] = f2bf(d0 * rstd * lng[t] + lnb[t]);
  x[t + 256] = f2bf(d1 * rstd * lng[t + 256] + lnb[t + 256]);
}

// ---------- 4. final LN + score ----------
__global__ __launch_bounds__(256) void ln_score_kernel(
    const float* __restrict__ X, const float* __restrict__ lng,
    const float* __restrict__ lnb, const float* __restrict__ Wsc,
    const float* __restrict__ bsc, float* __restrict__ scores) {
  const int token = blockIdx.x;
  const int t = threadIdx.x;
  __shared__ float s_red[4];
  const float* x = X + (size_t)token * ND;
  float v0 = x[t], v1 = x[t + 256];
  float mean = breduce256(v0 + v1, s_red) * (1.0f / ND);
  float d0 = v0 - mean, d1 = v1 - mean;
  float var = breduce256(d0 * d0 + d1 * d1, s_red) * (1.0f / ND);
  float rstd = rsqrtf(var + 1e-5f);
  float y0 = d0 * rstd * lng[t] + lnb[t];
  float y1 = d1 * rstd * lng[t + 256] + lnb[t + 256];
  float dot = breduce256(y0 * Wsc[t] + y1 * Wsc[t + 256], s_red);
  if (t == 0) scores[token] = dot + bsc[0];
}

// ---------- 5. softmax over S per batch ----------
__global__ __launch_bounds__(256) void softmax_kernel(
    const float* __restrict__ scores, float* __restrict__ probs) {
  const int b = blockIdx.x;
  const int t = threadIdx.x;
  __shared__ float s_red[4];
  const float* sc = scores + (size_t)b * NS;
  float v[4];
  float mx = -1e30f;
#pragma unroll
  for (int i = 0; i < 4; i++) { v[i] = sc[t + i * 256]; mx = fmaxf(mx, v[i]); }
#pragma unroll
  for (int off = 32; off > 0; off >>= 1) mx = fmaxf(mx, __shfl_down(mx, off));
  if ((t & 63) == 0) s_red[t >> 6] = mx;
  __syncthreads();
  mx = fmaxf(fmaxf(s_red[0], s_red[1]), fmaxf(s_red[2], s_red[3]));
  float e[4], sum = 0.f;
#pragma unroll
  for (int i = 0; i < 4; i++) { e[i] = expf(v[i] - mx); sum += e[i]; }
  sum = breduce256(sum, s_red);
  float inv = 1.f / sum;
#pragma unroll
  for (int i = 0; i < 4; i++) probs[(size_t)b * NS + t + i * 256] = e[i] * inv;
}

// ---------- 6. sparse scatter into spectrum ----------
__global__ __launch_bounds__(256) void scatter_kernel(
    const float* __restrict__ probs, const int* __restrict__ pidx,
    const float* __restrict__ pint, float* __restrict__ spect) {
  int token = blockIdx.x * 256 + threadIdx.x;
  int b = token >> 10;
  float p = probs[token];
  const int* idx = pidx + (size_t)token * NM;
  const float* wt = pint + (size_t)token * NM;
#pragma unroll
  for (int m = 0; m < NM; m++)
    atomicAdd(&spect[b * NBINS + idx[m]], wt[m] * p);
}

extern "C" void kernel_launch(void* const* d_in, const int* in_sizes, int n_in,
                              void* d_out, int out_size, void* d_ws, size_t ws_size,
                              hipStream_t stream) {
  const float* vert = (const float*)d_in[0];
  const float* mask = (const float*)d_in[1];
  const float* eloh = (const float*)d_in[2];
  const int* subs = (const int*)d_in[3];
  const int* pidx = (const int*)d_in[4];
  const float* pint = (const float*)d_in[5];
  const float* ln_sub_g = (const float*)d_in[6];
  const float* ln_sub_b = (const float*)d_in[7];
  const float* W_ih = (const float*)d_in[8];
  const float* W_hh = (const float*)d_in[9];
  const float* b_ih = (const float*)d_in[10];
  const float* b_hh = (const float*)d_in[11];
  const float* ln_post_g = (const float*)d_in[12];
  const float* ln_post_b = (const float*)d_in[13];
  const float* W1 = (const float*)d_in[14];
  const float* b1 = (const float*)d_in[15];
  const float* W2a = (const float*)d_in[16];
  const float* b2a = (const float*)d_in[17];
  const float* W2b = (const float*)d_in[18];
  const float* b2b = (const float*)d_in[19];
  const float* ln_pre_g = (const float*)d_in[20];
  const float* ln_pre_b = (const float*)d_in[21];
  const float* W_s = (const float*)d_in[22];
  const float* b_s = (const float*)d_in[23];

  float* out = (float*)d_out;            // [0,8192) spect, [8192,24576) probs
  float* probs = out + NB * NBINS;

  // ---- fixed region: scores + bf16 weights ----
  char* ws = (char*)d_ws;
  float* scores = (float*)ws;                       // 64 KB
  ushort_t* Wih_bf = (ushort_t*)(ws + 65536);       // 1536*128*2 = 393216
  ushort_t* Whh_bf = (ushort_t*)(ws + 458752);      // 1536*512*2 = 1572864
  ushort_t* W1_bf  = (ushort_t*)(ws + 2031616);     // 512*512*2 = 524288
  ushort_t* W2a_bf = (ushort_t*)(ws + 2555904);
  ushort_t* W2b_bf = (ushort_t*)(ws + 3080192);
  const size_t fixed = 3604480;

  // ---- ws-adaptive chunking; per-token bytes:
  //  Hf 2048 | Hb 1024 | F 256 | Gi 3072 | Gh 3072 | X0 1024 | X1 1024 | X2 1024 = 12544
  const size_t per_tok = 12544;
  int T = NTOK;
  while (T > 1024 && fixed + (size_t)T * per_tok > ws_size) T >>= 1;
  const int nchunks = NTOK / T;

  char* cb = ws + fixed;
  float*    Hf = (float*)cb;                              cb += (size_t)T * 2048;
  ushort_t* Hb = (ushort_t*)cb;                           cb += (size_t)T * 1024;
  ushort_t* F  = (ushort_t*)cb;                           cb += (size_t)T * 256;
  ushort_t* Gi = (ushort_t*)cb;                           cb += (size_t)T * 3072;
  ushort_t* Gh = (ushort_t*)cb;                           cb += (size_t)T * 3072;
  ushort_t* X0 = (ushort_t*)cb;                           cb += (size_t)T * 1024;
  ushort_t* X1 = (ushort_t*)cb;                           cb += (size_t)T * 1024;
  ushort_t* X2 = (ushort_t*)cb;
  float*    X3 = Hf;   // H dead after gate_ln

  hipMemsetAsync(d_out, 0, NB * NBINS * sizeof(float), stream);

  // weight conversion (runs every call; ~3.5 MB total, negligible)
  cvt_wih_kernel<<<(1536 * NFEP) / 256, 256, 0, stream>>>(W_ih, Wih_bf);
  cvt_bf16_kernel<<<(1536 * NG) / 256, 256, 0, stream>>>(W_hh, Whh_bf, 1536 * NG);
  cvt_bf16_kernel<<<(ND * NG) / 256, 256, 0, stream>>>(W1, W1_bf, ND * NG);
  cvt_bf16_kernel<<<(ND * ND) / 256, 256, 0, stream>>>(W2a, W2a_bf, ND * ND);
  cvt_bf16_kernel<<<(ND * ND) / 256, 256, 0, stream>>>(W2b, W2b_bf, ND * ND);

  for (int c = 0; c < nchunks; c++) {
    const int tok0 = c * T;
    pool_kernel<<<T, 256, 0, stream>>>(vert, mask, eloh, subs, ln_sub_g, ln_sub_b,
                                       Hf, Hb, F, tok0);

    dim3 g1(T / 128, 1536 / 128);
    gemm_bf16<<<g1, 256, 0, stream>>>(F, Wih_bf, b_ih, Gi, NFEP, 1536, 3);
    gemm_bf16<<<g1, 256, 0, stream>>>(Hb, Whh_bf, b_hh, Gh, NG, 1536, 3);

    gate_ln_kernel<<<T, 256, 0, stream>>>(Gi, Gh, Hf, ln_post_g, ln_post_b, X0);

    dim3 g2(T / 128, ND / 128);
    gemm_bf16<<<g2, 256, 0, stream>>>(X0, W1_bf, b1, X1, NG, ND, 1);
    gemm_bf16<<<g2, 256, 0, stream>>>(X1, W2a_bf, b2a, X2, ND, ND, 1);
    gemm_bf16<<<g2, 256, 0, stream>>>(X2, W2b_bf, b2b, X3, ND, ND, 2);

    ln_score_kernel<<<T, 256, 0, stream>>>(X3, ln_pre_g, ln_pre_b, W_s, b_s, scores + tok0);
  }

  softmax_kernel<<<NB, 256, 0, stream>>>(scores, probs);
  scatter_kernel<<<NTOK / 256, 256, 0, stream>>>(probs, pidx, pint, out);
}

// Round 5
// 306.754 us; speedup vs baseline: 3.4153x; 1.1279x over previous
//
#include <hip/hip_runtime.h>

#define NB 16
#define NA 32
#define NG 512
#define NS 1024
#define NM 8
#define NE 5
#define NOH 20
#define NFE 100
#define NFEP 128   // padded formula width for K%32==0
#define ND 512
#define NBINS 512
#define NTOK (NB * NS)

typedef unsigned short ushort_t;
typedef __attribute__((ext_vector_type(8))) short bf16x8;
typedef __attribute__((ext_vector_type(4))) float f32x4;

__device__ __forceinline__ ushort_t f2bf(float x) {
  union { float f; unsigned u; } v; v.f = x;
  unsigned r = v.u + 0x7FFF + ((v.u >> 16) & 1);   // RNE
  return (ushort_t)(r >> 16);
}
__device__ __forceinline__ float bf2f(ushort_t b) {
  union { unsigned u; float f; } v; v.u = ((unsigned)b) << 16;
  return v.f;
}

__device__ __forceinline__ void gload_lds16(const void* g, void* l) {
  __builtin_amdgcn_global_load_lds(
      (const __attribute__((address_space(1))) void*)g,
      (__attribute__((address_space(3))) void*)l, 16, 0, 0);
}

// ---------- block reduce (256 threads, 4 waves of 64) ----------
__device__ inline float breduce256(float v, float* s) {
#pragma unroll
  for (int off = 32; off > 0; off >>= 1) v += __shfl_down(v, off);
  __syncthreads();
  if ((threadIdx.x & 63) == 0) s[threadIdx.x >> 6] = v;
  __syncthreads();
  return s[0] + s[1] + s[2] + s[3];
}

// ---------- weight conversion (all 5 weights in one launch) ----------
__global__ __launch_bounds__(256) void cvt_all_kernel(
    const float* __restrict__ Wih, const float* __restrict__ Whh,
    const float* __restrict__ W1, const float* __restrict__ W2a,
    const float* __restrict__ W2b,
    ushort_t* __restrict__ o_ih, ushort_t* __restrict__ o_hh,
    ushort_t* __restrict__ o1, ushort_t* __restrict__ o2a,
    ushort_t* __restrict__ o2b) {
  int i = blockIdx.x * 256 + threadIdx.x;
  if (i < 1536 * NFEP) {   // W_ih [1536,100] -> [1536,128] zero-padded
    int r = i >> 7, c = i & 127;
    o_ih[i] = (c < NFE) ? f2bf(Wih[r * NFE + c]) : (ushort_t)0;
    return;
  }
  i -= 1536 * NFEP;
  if (i < 1536 * NG) { o_hh[i] = f2bf(Whh[i]); return; }
  i -= 1536 * NG;
  if (i < ND * NG) { o1[i] = f2bf(W1[i]); return; }
  i -= ND * NG;
  if (i < ND * ND) { o2a[i] = f2bf(W2a[i]); return; }
  i -= ND * ND;
  if (i < ND * ND) o2b[i] = f2bf(W2b[i]);
}

// ---------- prep: VmT[b][f][a] = bf16(vert*mask^2), S_bf = bf16(subs) ----------
__global__ __launch_bounds__(256) void prep_kernel(
    const float* __restrict__ vert, const float* __restrict__ mask,
    const int* __restrict__ subs, ushort_t* __restrict__ VmT,
    ushort_t* __restrict__ S_bf) {
  int i = blockIdx.x * 256 + threadIdx.x;
  const int nV = NB * NG * NA;   // 262144
  if (i < nV) {
    int b = i / (NG * NA); int rem = i % (NG * NA);
    int f = rem >> 5, a = rem & 31;
    float mk = mask[b * NA + a];
    VmT[i] = f2bf(vert[(size_t)b * NA * NG + a * NG + f] * mk * mk);
    return;
  }
  int j = i - nV;
  if (j < NTOK * NA) S_bf[j] = f2bf((float)subs[j]);   // 0/1 exact
}

// ---------- invcnt: per-token subset-size inverse + element counts (fp32 exact) ----------
__global__ __launch_bounds__(256) void invcnt_kernel(
    const int* __restrict__ subs, const float* __restrict__ mask,
    const float* __restrict__ eloh, float* __restrict__ tcd) {
  int token = blockIdx.x * 256 + threadIdx.x;
  int b = token >> 10;
  const int* srow = subs + (size_t)token * NA;
  float cnt[NE] = {0.f, 0.f, 0.f, 0.f, 0.f};
  float z = 0.f;
  for (int a = 0; a < NA; a++) {
    float sb = (float)srow[a];
    z += sb * mask[b * NA + a];
    const float* eo = eloh + (size_t)(b * NA + a) * NE;
#pragma unroll
    for (int e = 0; e < NE; e++) cnt[e] += eo[e] * sb;
  }
  float* o = tcd + (size_t)token * 8;
#pragma unroll
  for (int e = 0; e < NE; e++) o[e] = cnt[e];
  o[5] = 1.0f / (z + 1e-4f);
}

// ---------- pool GEMM: SWV[ltok][f] = (subs @ VmT^T) * inv  (K=32, one MFMA step) ----------
__global__ __launch_bounds__(256) void pool_gemm(
    const ushort_t* __restrict__ S_bf, const ushort_t* __restrict__ VmT,
    const float* __restrict__ tcd, float* __restrict__ SWV, int tok0) {
  __shared__ ushort_t As[128 * 32];
  __shared__ ushort_t Bs[128 * 32];
  const int t = threadIdx.x;
  const int w = t >> 6, lane = t & 63;
  const int wr = w >> 1, wc = w & 1;
  const int bm = blockIdx.x * 128;   // chunk-local token base
  const int bn = blockIdx.y * 128;   // f base
  const int b = (tok0 + bm) >> 10;   // 128 | 1024 so tile is single-batch
  const int srow = lane >> 2, scol = (lane & 3) * 8;
  const ushort_t* Bbase = VmT + (size_t)b * NG * NA;
  gload_lds16(S_bf + (size_t)(tok0 + bm + (0 * 4 + w) * 16 + srow) * 32 + scol, &As[(0 * 4 + w) * 512]);
  gload_lds16(S_bf + (size_t)(tok0 + bm + (1 * 4 + w) * 16 + srow) * 32 + scol, &As[(1 * 4 + w) * 512]);
  gload_lds16(Bbase + (size_t)(bn + (0 * 4 + w) * 16 + srow) * 32 + scol, &Bs[(0 * 4 + w) * 512]);
  gload_lds16(Bbase + (size_t)(bn + (1 * 4 + w) * 16 + srow) * 32 + scol, &Bs[(1 * 4 + w) * 512]);
  __syncthreads();

  const int lr = lane & 15, lq = lane >> 4;
  f32x4 acc[4][4];
#pragma unroll
  for (int m = 0; m < 4; m++)
#pragma unroll
    for (int n = 0; n < 4; n++) acc[m][n] = (f32x4)0.f;
  bf16x8 a[4], bb[4];
#pragma unroll
  for (int m = 0; m < 4; m++)
    a[m] = *(const bf16x8*)&As[(wr * 64 + m * 16 + lr) * 32 + lq * 8];
#pragma unroll
  for (int n = 0; n < 4; n++)
    bb[n] = *(const bf16x8*)&Bs[(wc * 64 + n * 16 + lr) * 32 + lq * 8];
#pragma unroll
  for (int m = 0; m < 4; m++)
#pragma unroll
    for (int n = 0; n < 4; n++)
      acc[m][n] = __builtin_amdgcn_mfma_f32_16x16x32_bf16(a[m], bb[n], acc[m][n], 0, 0, 0);

#pragma unroll
  for (int n = 0; n < 4; n++) {
    const int col = bn + wc * 64 + n * 16 + lr;
#pragma unroll
    for (int m = 0; m < 4; m++) {
      f32x4 v = acc[m][n];
#pragma unroll
      for (int r = 0; r < 4; r++) {
        int row = bm + wr * 64 + m * 16 + lq * 4 + r;
        float inv = tcd[(size_t)(tok0 + row) * 8 + 5];
        SWV[(size_t)row * NG + col] = v[r] * inv;
      }
    }
  }
}

// ---------- finish: LN(swv_mean) -> Hb bf16, thermometer -> F bf16 ----------
__global__ __launch_bounds__(256) void finish_kernel(
    const float* __restrict__ SWV, const float* __restrict__ tcd,
    const float* __restrict__ lng, const float* __restrict__ lnb,
    ushort_t* __restrict__ Hb, ushort_t* __restrict__ F, int tok0) {
  const int ltok = blockIdx.x;
  const int token = tok0 + ltok;
  const int t = threadIdx.x;
  __shared__ float s_red[4];
  float2 v = *(const float2*)&SWV[(size_t)ltok * NG + 2 * t];
  float mean = breduce256(v.x + v.y, s_red) * (1.0f / NG);
  float d0 = v.x - mean, d1 = v.y - mean;
  float var = breduce256(d0 * d0 + d1 * d1, s_red) * (1.0f / NG);
  float rstd = rsqrtf(var + 1e-5f);
  float2 g = *(const float2*)&lng[2 * t];
  float2 be = *(const float2*)&lnb[2 * t];
  ushort2 ho;
  ho.x = f2bf(d0 * rstd * g.x + be.x);
  ho.y = f2bf(d1 * rstd * g.y + be.y);
  *(ushort2*)&Hb[(size_t)ltok * NG + 2 * t] = ho;
  if (t < NFEP) {
    float vF = 0.f;
    if (t < NFE) {
      int e = t / NOH, o = t % NOH;
      vF = ((float)o < tcd[(size_t)token * 8 + e]) ? 1.0f : 0.0f;
    }
    F[(size_t)ltok * NFEP + t] = f2bf(vF);
  }
}

// ---------- bf16 MFMA GEMM: C[M,Dout] = act(A[M,K] @ W[Dout,K]^T + bias) ----------
// BM=BN=128, BK=32, 4 waves (2x2), 4x4 16x16x32 frags per wave
// mode: 1 = bf16 out relu, 3 = bf16 out no act
__global__ __launch_bounds__(256) void gemm_bf16(
    const ushort_t* __restrict__ A, const ushort_t* __restrict__ W,
    const float* __restrict__ bias, ushort_t* __restrict__ C,
    int K, int Dout, int mode) {
  __shared__ ushort_t As[128 * 32];
  __shared__ ushort_t Bs[128 * 32];
  const int t = threadIdx.x;
  const int w = t >> 6;
  const int lane = t & 63;
  const int wr = w >> 1, wc = w & 1;
  const int bm = blockIdx.x * 128, bn = blockIdx.y * 128;

  const int srow = lane >> 2;
  const int scol = (lane & 3) * 8;
  const ushort_t* Ag0 = A + (size_t)(bm + (0 * 4 + w) * 16 + srow) * K + scol;
  const ushort_t* Ag1 = A + (size_t)(bm + (1 * 4 + w) * 16 + srow) * K + scol;
  const ushort_t* Wg0 = W + (size_t)(bn + (0 * 4 + w) * 16 + srow) * K + scol;
  const ushort_t* Wg1 = W + (size_t)(bn + (1 * 4 + w) * 16 + srow) * K + scol;
  ushort_t* ldsA0 = &As[(0 * 4 + w) * 512];
  ushort_t* ldsA1 = &As[(1 * 4 + w) * 512];
  ushort_t* ldsB0 = &Bs[(0 * 4 + w) * 512];
  ushort_t* ldsB1 = &Bs[(1 * 4 + w) * 512];

  const int lr = lane & 15;
  const int lq = lane >> 4;

  f32x4 acc[4][4];
#pragma unroll
  for (int m = 0; m < 4; m++)
#pragma unroll
    for (int n = 0; n < 4; n++) acc[m][n] = (f32x4)0.f;

  for (int k0 = 0; k0 < K; k0 += 32) {
    gload_lds16(Ag0 + k0, ldsA0);
    gload_lds16(Ag1 + k0, ldsA1);
    gload_lds16(Wg0 + k0, ldsB0);
    gload_lds16(Wg1 + k0, ldsB1);
    __syncthreads();
    bf16x8 a[4], b[4];
#pragma unroll
    for (int m = 0; m < 4; m++)
      a[m] = *(const bf16x8*)&As[(wr * 64 + m * 16 + lr) * 32 + lq * 8];
#pragma unroll
    for (int n = 0; n < 4; n++)
      b[n] = *(const bf16x8*)&Bs[(wc * 64 + n * 16 + lr) * 32 + lq * 8];
#pragma unroll
    for (int m = 0; m < 4; m++)
#pragma unroll
      for (int n = 0; n < 4; n++)
        acc[m][n] = __builtin_amdgcn_mfma_f32_16x16x32_bf16(a[m], b[n], acc[m][n], 0, 0, 0);
    __syncthreads();
  }

  // epilogue: C/D layout col = lane&15, row = (lane>>4)*4 + r
#pragma unroll
  for (int n = 0; n < 4; n++) {
    const int col = bn + wc * 64 + n * 16 + lr;
    const float bv = bias[col];
#pragma unroll
    for (int m = 0; m < 4; m++) {
      f32x4 v = acc[m][n];
#pragma unroll
      for (int r = 0; r < 4; r++) {
        int row = bm + wr * 64 + m * 16 + lq * 4 + r;
        float u = v[r] + bv;
        if (mode == 1) u = fmaxf(u, 0.f);
        C[(size_t)row * Dout + col] = f2bf(u);
      }
    }
  }
}

// ---------- GRU gates + post-LN (bf16 in, bf16 out, ushort2 loads) ----------
__global__ __launch_bounds__(256) void gate_ln_kernel(
    const ushort_t* __restrict__ Gi, const ushort_t* __restrict__ Gh,
    const ushort_t* __restrict__ Hb, const float* __restrict__ lng,
    const float* __restrict__ lnb, ushort_t* __restrict__ X0) {
  const int token = blockIdx.x;
  const int t = threadIdx.x;
  __shared__ float s_red[4];
  const ushort_t* gi = Gi + (size_t)token * 1536;
  const ushort_t* gh = Gh + (size_t)token * 1536;
  ushort2 gir = *(const ushort2*)&gi[2 * t];
  ushort2 giz = *(const ushort2*)&gi[NG + 2 * t];
  ushort2 gin = *(const ushort2*)&gi[2 * NG + 2 * t];
  ushort2 ghr = *(const ushort2*)&gh[2 * t];
  ushort2 ghz = *(const ushort2*)&gh[NG + 2 * t];
  ushort2 ghn = *(const ushort2*)&gh[2 * NG + 2 * t];
  ushort2 hh = *(const ushort2*)&Hb[(size_t)token * NG + 2 * t];
  float c[2];
  {
    float r0 = 1.f / (1.f + expf(-(bf2f(gir.x) + bf2f(ghr.x))));
    float z0 = 1.f / (1.f + expf(-(bf2f(giz.x) + bf2f(ghz.x))));
    float n0 = tanhf(bf2f(gin.x) + r0 * bf2f(ghn.x));
    c[0] = (1.f - z0) * n0 + z0 * bf2f(hh.x);
    float r1 = 1.f / (1.f + expf(-(bf2f(gir.y) + bf2f(ghr.y))));
    float z1 = 1.f / (1.f + expf(-(bf2f(giz.y) + bf2f(ghz.y))));
    float n1 = tanhf(bf2f(gin.y) + r1 * bf2f(ghn.y));
    c[1] = (1.f - z1) * n1 + z1 * bf2f(hh.y);
  }
  float mean = breduce256(c[0] + c[1], s_red) * (1.0f / NG);
  float d0 = c[0] - mean, d1 = c[1] - mean;
  float var = breduce256(d0 * d0 + d1 * d1, s_red) * (1.0f / NG);
  float rstd = rsqrtf(var + 1e-5f);
  float2 g = *(const float2*)&lng[2 * t];
  float2 be = *(const float2*)&lnb[2 * t];
  ushort2 xo;
  xo.x = f2bf(d0 * rstd * g.x + be.x);
  xo.y = f2bf(d1 * rstd * g.y + be.y);
  *(ushort2*)&X0[(size_t)token * NG + 2 * t] = xo;
}

// ---------- final LN + score (bf16 in) ----------
__global__ __launch_bounds__(256) void ln_score_kernel(
    const ushort_t* __restrict__ X, const float* __restrict__ lng,
    const float* __restrict__ lnb, const float* __restrict__ Wsc,
    const float* __restrict__ bsc, float* __restrict__ scores) {
  const int token = blockIdx.x;
  const int t = threadIdx.x;
  __shared__ float s_red[4];
  ushort2 xx = *(const ushort2*)&X[(size_t)token * ND + 2 * t];
  float v0 = bf2f(xx.x), v1 = bf2f(xx.y);
  float mean = breduce256(v0 + v1, s_red) * (1.0f / ND);
  float d0 = v0 - mean, d1 = v1 - mean;
  float var = breduce256(d0 * d0 + d1 * d1, s_red) * (1.0f / ND);
  float rstd = rsqrtf(var + 1e-5f);
  float2 g = *(const float2*)&lng[2 * t];
  float2 be = *(const float2*)&lnb[2 * t];
  float2 wv = *(const float2*)&Wsc[2 * t];
  float y0 = d0 * rstd * g.x + be.x;
  float y1 = d1 * rstd * g.y + be.y;
  float dot = breduce256(y0 * wv.x + y1 * wv.y, s_red);
  if (t == 0) scores[token] = dot + bsc[0];
}

// ---------- softmax over S per batch ----------
__global__ __launch_bounds__(256) void softmax_kernel(
    const float* __restrict__ scores, float* __restrict__ probs) {
  const int b = blockIdx.x;
  const int t = threadIdx.x;
  __shared__ float s_red[4];
  const float* sc = scores + (size_t)b * NS;
  float v[4];
  float mx = -1e30f;
#pragma unroll
  for (int i = 0; i < 4; i++) { v[i] = sc[t + i * 256]; mx = fmaxf(mx, v[i]); }
#pragma unroll
  for (int off = 32; off > 0; off >>= 1) mx = fmaxf(mx, __shfl_down(mx, off));
  if ((t & 63) == 0) s_red[t >> 6] = mx;
  __syncthreads();
  mx = fmaxf(fmaxf(s_red[0], s_red[1]), fmaxf(s_red[2], s_red[3]));
  float e[4], sum = 0.f;
#pragma unroll
  for (int i = 0; i < 4; i++) { e[i] = expf(v[i] - mx); sum += e[i]; }
  sum = breduce256(sum, s_red);
  float inv = 1.f / sum;
#pragma unroll
  for (int i = 0; i < 4; i++) probs[(size_t)b * NS + t + i * 256] = e[i] * inv;
}

// ---------- sparse scatter into spectrum ----------
__global__ __launch_bounds__(256) void scatter_kernel(
    const float* __restrict__ probs, const int* __restrict__ pidx,
    const float* __restrict__ pint, float* __restrict__ spect) {
  int token = blockIdx.x * 256 + threadIdx.x;
  int b = token >> 10;
  float p = probs[token];
  const int* idx = pidx + (size_t)token * NM;
  const float* wt = pint + (size_t)token * NM;
#pragma unroll
  for (int m = 0; m < NM; m++)
    atomicAdd(&spect[b * NBINS + idx[m]], wt[m] * p);
}

extern "C" void kernel_launch(void* const* d_in, const int* in_sizes, int n_in,
                              void* d_out, int out_size, void* d_ws, size_t ws_size,
                              hipStream_t stream) {
  const float* vert = (const float*)d_in[0];
  const float* mask = (const float*)d_in[1];
  const float* eloh = (const float*)d_in[2];
  const int* subs = (const int*)d_in[3];
  const int* pidx = (const int*)d_in[4];
  const float* pint = (const float*)d_in[5];
  const float* ln_sub_g = (const float*)d_in[6];
  const float* ln_sub_b = (const float*)d_in[7];
  const float* W_ih = (const float*)d_in[8];
  const float* W_hh = (const float*)d_in[9];
  const float* b_ih = (const float*)d_in[10];
  const float* b_hh = (const float*)d_in[11];
  const float* ln_post_g = (const float*)d_in[12];
  const float* ln_post_b = (const float*)d_in[13];
  const float* W1 = (const float*)d_in[14];
  const float* b1 = (const float*)d_in[15];
  const float* W2a = (const float*)d_in[16];
  const float* b2a = (const float*)d_in[17];
  const float* W2b = (const float*)d_in[18];
  const float* b2b = (const float*)d_in[19];
  const float* ln_pre_g = (const float*)d_in[20];
  const float* ln_pre_b = (const float*)d_in[21];
  const float* W_s = (const float*)d_in[22];
  const float* b_s = (const float*)d_in[23];

  float* out = (float*)d_out;            // [0,8192) spect, [8192,24576) probs
  float* probs = out + NB * NBINS;

  // ---- fixed region ----
  char* ws = (char*)d_ws;
  float* scores = (float*)ws;                       // 64 KB
  ushort_t* Wih_bf = (ushort_t*)(ws + 65536);       // 1536*128*2 = 393216
  ushort_t* Whh_bf = (ushort_t*)(ws + 458752);      // 1536*512*2 = 1572864
  ushort_t* W1_bf  = (ushort_t*)(ws + 2031616);     // 512*512*2 = 524288
  ushort_t* W2a_bf = (ushort_t*)(ws + 2555904);
  ushort_t* W2b_bf = (ushort_t*)(ws + 3080192);
  ushort_t* VmT    = (ushort_t*)(ws + 3604480);     // 16*512*32*2 = 524288
  ushort_t* S_bf   = (ushort_t*)(ws + 4128768);     // 16384*32*2 = 1048576
  float*    tcd    = (float*)(ws + 5177344);        // 16384*8*4 = 524288
  const size_t fixed = 5701632;

  // ---- chunked region; per-token bytes:
  //  SWV 2048 | Hb 1024 | F 256 | Gi 3072 | Gh 3072 | X0 1024 = 10496
  const size_t per_tok = 10496;
  int T = NTOK;
  while (T > 1024 && fixed + (size_t)T * per_tok > ws_size) T >>= 1;
  const int nchunks = NTOK / T;

  char* cb = ws + fixed;
  float*    SWV = (float*)cb;                             cb += (size_t)T * 2048;
  ushort_t* Hb  = (ushort_t*)cb;                          cb += (size_t)T * 1024;
  ushort_t* F   = (ushort_t*)cb;                          cb += (size_t)T * 256;
  ushort_t* Gi  = (ushort_t*)cb;                          cb += (size_t)T * 3072;
  ushort_t* Gh  = (ushort_t*)cb;                          cb += (size_t)T * 3072;
  ushort_t* X0  = (ushort_t*)cb;
  ushort_t* X1  = Gi;   // Gi dead after gate_ln
  ushort_t* X2  = Gh;   // Gh dead after gate_ln
  ushort_t* X3  = X0;   // X0 dead after W1 GEMM

  hipMemsetAsync(d_out, 0, NB * NBINS * sizeof(float), stream);

  cvt_all_kernel<<<(1536 * NFEP + 1536 * NG + 3 * ND * ND) / 256, 256, 0, stream>>>(
      W_ih, W_hh, W1, W2a, W2b, Wih_bf, Whh_bf, W1_bf, W2a_bf, W2b_bf);
  prep_kernel<<<(NB * NG * NA + NTOK * NA) / 256, 256, 0, stream>>>(
      vert, mask, subs, VmT, S_bf);
  invcnt_kernel<<<NTOK / 256, 256, 0, stream>>>(subs, mask, eloh, tcd);

  for (int c = 0; c < nchunks; c++) {
    const int tok0 = c * T;

    dim3 gp(T / 128, NG / 128);
    pool_gemm<<<gp, 256, 0, stream>>>(S_bf, VmT, tcd, SWV, tok0);
    finish_kernel<<<T, 256, 0, stream>>>(SWV, tcd, ln_sub_g, ln_sub_b, Hb, F, tok0);

    dim3 g1(T / 128, 1536 / 128);
    gemm_bf16<<<g1, 256, 0, stream>>>(F, Wih_bf, b_ih, Gi, NFEP, 1536, 3);
    gemm_bf16<<<g1, 256, 0, stream>>>(Hb, Whh_bf, b_hh, Gh, NG, 1536, 3);

    gate_ln_kernel<<<T, 256, 0, stream>>>(Gi, Gh, Hb, ln_post_g, ln_post_b, X0);

    dim3 g2(T / 128, ND / 128);
    gemm_bf16<<<g2, 256, 0, stream>>>(X0, W1_bf, b1, X1, NG, ND, 1);
    gemm_bf16<<<g2, 256, 0, stream>>>(X1, W2a_bf, b2a, X2, ND, ND, 1);
    gemm_bf16<<<g2, 256, 0, stream>>>(X2, W2b_bf, b2b, X3, ND, ND, 1);

    ln_score_kernel<<<T, 256, 0, stream>>>(X3, ln_pre_g, ln_pre_b, W_s, b_s, scores + tok0);
  }

  softmax_kernel<<<NB, 256, 0, stream>>>(scores, probs);
  scatter_kernel<<<NTOK / 256, 256, 0, stream>>>(probs, pidx, pint, out);
}

// Round 6
// 301.089 us; speedup vs baseline: 3.4795x; 1.0188x over previous
//
#include <hip/hip_runtime.h>

#define NB 16
#define NA 32
#define NG 512
#define NS 1024
#define NM 8
#define NE 5
#define NOH 20
#define NFE 100
#define NFEP 128   // padded formula width for K%32==0
#define ND 512
#define NBINS 512
#define NTOK (NB * NS)

typedef unsigned short ushort_t;
typedef __attribute__((ext_vector_type(8))) short bf16x8;
typedef __attribute__((ext_vector_type(4))) float f32x4;

__device__ __forceinline__ ushort_t f2bf(float x) {
  union { float f; unsigned u; } v; v.f = x;
  unsigned r = v.u + 0x7FFF + ((v.u >> 16) & 1);   // RNE
  return (ushort_t)(r >> 16);
}
__device__ __forceinline__ float bf2f(ushort_t b) {
  union { unsigned u; float f; } v; v.u = ((unsigned)b) << 16;
  return v.f;
}

__device__ __forceinline__ void gload_lds16(const void* g, void* l) {
  __builtin_amdgcn_global_load_lds(
      (const __attribute__((address_space(1))) void*)g,
      (__attribute__((address_space(3))) void*)l, 16, 0, 0);
}

// ---------- block reduce (256 threads, 4 waves of 64) ----------
__device__ inline float breduce256(float v, float* s) {
#pragma unroll
  for (int off = 32; off > 0; off >>= 1) v += __shfl_down(v, off);
  __syncthreads();
  if ((threadIdx.x & 63) == 0) s[threadIdx.x >> 6] = v;
  __syncthreads();
  return s[0] + s[1] + s[2] + s[3];
}

// ---------- fused setup: invcnt | weight cvt | VmT prep | S_bf cvt ----------
// index space: [0,NTOK) invcnt; then Wih pad; Whh; W1; W2a; W2b; VmT; S_bf
__global__ __launch_bounds__(256) void setup_kernel(
    const float* __restrict__ vert, const float* __restrict__ mask,
    const float* __restrict__ eloh, const int* __restrict__ subs,
    const float* __restrict__ Wih, const float* __restrict__ Whh,
    const float* __restrict__ W1, const float* __restrict__ W2a,
    const float* __restrict__ W2b,
    float* __restrict__ tcd,
    ushort_t* __restrict__ o_ih, ushort_t* __restrict__ o_hh,
    ushort_t* __restrict__ o1, ushort_t* __restrict__ o2a,
    ushort_t* __restrict__ o2b,
    ushort_t* __restrict__ VmT, ushort_t* __restrict__ S_bf) {
  int i = blockIdx.x * 256 + threadIdx.x;
  if (i < NTOK) {   // per-token subset size inverse + element counts (fp32 exact)
    int b = i >> 10;
    const int* srow = subs + (size_t)i * NA;
    float cnt[NE] = {0.f, 0.f, 0.f, 0.f, 0.f};
    float z = 0.f;
    for (int a = 0; a < NA; a++) {
      float sb = (float)srow[a];
      z += sb * mask[b * NA + a];
      const float* eo = eloh + (size_t)(b * NA + a) * NE;
#pragma unroll
      for (int e = 0; e < NE; e++) cnt[e] += eo[e] * sb;
    }
    float* o = tcd + (size_t)i * 8;
#pragma unroll
    for (int e = 0; e < NE; e++) o[e] = cnt[e];
    o[5] = 1.0f / (z + 1e-4f);
    return;
  }
  i -= NTOK;
  if (i < 1536 * NFEP) {   // W_ih [1536,100] -> [1536,128] zero-padded
    int r = i >> 7, c = i & 127;
    o_ih[i] = (c < NFE) ? f2bf(Wih[r * NFE + c]) : (ushort_t)0;
    return;
  }
  i -= 1536 * NFEP;
  if (i < 1536 * NG) { o_hh[i] = f2bf(Whh[i]); return; }
  i -= 1536 * NG;
  if (i < ND * NG) { o1[i] = f2bf(W1[i]); return; }
  i -= ND * NG;
  if (i < ND * ND) { o2a[i] = f2bf(W2a[i]); return; }
  i -= ND * ND;
  if (i < ND * ND) { o2b[i] = f2bf(W2b[i]); return; }
  i -= ND * ND;
  const int nV = NB * NG * NA;
  if (i < nV) {   // VmT[b][f][a] = bf16(vert*mask^2)
    int b = i / (NG * NA); int rem = i % (NG * NA);
    int f = rem >> 5, a = rem & 31;
    float mk = mask[b * NA + a];
    VmT[i] = f2bf(vert[(size_t)b * NA * NG + a * NG + f] * mk * mk);
    return;
  }
  i -= nV;
  if (i < NTOK * NA) S_bf[i] = f2bf((float)subs[i]);   // 0/1 exact
}

// ---------- pool GEMM: SWV[ltok][f] = (subs @ VmT^T) * inv  (K=32, one MFMA step) ----------
__global__ __launch_bounds__(256) void pool_gemm(
    const ushort_t* __restrict__ S_bf, const ushort_t* __restrict__ VmT,
    const float* __restrict__ tcd, float* __restrict__ SWV, int tok0) {
  __shared__ ushort_t As[128 * 32];
  __shared__ ushort_t Bs[128 * 32];
  const int t = threadIdx.x;
  const int w = t >> 6, lane = t & 63;
  const int wr = w >> 1, wc = w & 1;
  const int bm = blockIdx.x * 128;   // chunk-local token base
  const int bn = blockIdx.y * 128;   // f base
  const int b = (tok0 + bm) >> 10;   // 128 | 1024 so tile is single-batch
  const int srow = lane >> 2, scol = (lane & 3) * 8;
  const ushort_t* Bbase = VmT + (size_t)b * NG * NA;
  gload_lds16(S_bf + (size_t)(tok0 + bm + w * 16 + srow) * 32 + scol, &As[w * 512]);
  gload_lds16(S_bf + (size_t)(tok0 + bm + 64 + w * 16 + srow) * 32 + scol, &As[2048 + w * 512]);
  gload_lds16(Bbase + (size_t)(bn + w * 16 + srow) * 32 + scol, &Bs[w * 512]);
  gload_lds16(Bbase + (size_t)(bn + 64 + w * 16 + srow) * 32 + scol, &Bs[2048 + w * 512]);
  __syncthreads();

  const int lr = lane & 15, lq = lane >> 4;
  f32x4 acc[4][4];
#pragma unroll
  for (int m = 0; m < 4; m++)
#pragma unroll
    for (int n = 0; n < 4; n++) acc[m][n] = (f32x4)0.f;
  bf16x8 a[4], bb[4];
#pragma unroll
  for (int m = 0; m < 4; m++)
    a[m] = *(const bf16x8*)&As[(wr * 64 + m * 16 + lr) * 32 + lq * 8];
#pragma unroll
  for (int n = 0; n < 4; n++)
    bb[n] = *(const bf16x8*)&Bs[(wc * 64 + n * 16 + lr) * 32 + lq * 8];
#pragma unroll
  for (int m = 0; m < 4; m++)
#pragma unroll
    for (int n = 0; n < 4; n++)
      acc[m][n] = __builtin_amdgcn_mfma_f32_16x16x32_bf16(a[m], bb[n], acc[m][n], 0, 0, 0);

#pragma unroll
  for (int n = 0; n < 4; n++) {
    const int col = bn + wc * 64 + n * 16 + lr;
#pragma unroll
    for (int m = 0; m < 4; m++) {
      f32x4 v = acc[m][n];
#pragma unroll
      for (int r = 0; r < 4; r++) {
        int row = bm + wr * 64 + m * 16 + lq * 4 + r;
        float inv = tcd[(size_t)(tok0 + row) * 8 + 5];
        SWV[(size_t)row * NG + col] = v[r] * inv;
      }
    }
  }
}

// ---------- finish: LN(swv_mean) -> Hb bf16, thermometer -> F bf16 ----------
__global__ __launch_bounds__(256) void finish_kernel(
    const float* __restrict__ SWV, const float* __restrict__ tcd,
    const float* __restrict__ lng, const float* __restrict__ lnb,
    ushort_t* __restrict__ Hb, ushort_t* __restrict__ F, int tok0) {
  const int ltok = blockIdx.x;
  const int token = tok0 + ltok;
  const int t = threadIdx.x;
  __shared__ float s_red[4];
  float2 v = *(const float2*)&SWV[(size_t)ltok * NG + 2 * t];
  float mean = breduce256(v.x + v.y, s_red) * (1.0f / NG);
  float d0 = v.x - mean, d1 = v.y - mean;
  float var = breduce256(d0 * d0 + d1 * d1, s_red) * (1.0f / NG);
  float rstd = rsqrtf(var + 1e-5f);
  float2 g = *(const float2*)&lng[2 * t];
  float2 be = *(const float2*)&lnb[2 * t];
  ushort2 ho;
  ho.x = f2bf(d0 * rstd * g.x + be.x);
  ho.y = f2bf(d1 * rstd * g.y + be.y);
  *(ushort2*)&Hb[(size_t)ltok * NG + 2 * t] = ho;
  if (t < NFEP) {
    float vF = 0.f;
    if (t < NFE) {
      int e = t / NOH, o = t % NOH;
      vF = ((float)o < tcd[(size_t)token * 8 + e]) ? 1.0f : 0.0f;
    }
    F[(size_t)ltok * NFEP + t] = f2bf(vF);
  }
}

// ---------- bf16 MFMA GEMM, double-buffered prefetch (T3 minimum 2-phase) ----------
// BM=BN=128, BK=32, 4 waves (2x2), 4x4 16x16x32 frags per wave
// K-step: issue next tile's global_load_lds BEFORE current compute; ONE barrier/step.
// mode: 1 = bf16 out relu, 3 = bf16 out no act
__global__ __launch_bounds__(256) void gemm_bf16(
    const ushort_t* __restrict__ A, const ushort_t* __restrict__ W,
    const float* __restrict__ bias, ushort_t* __restrict__ C,
    int K, int Dout, int mode) {
  __shared__ ushort_t As[2][4096];
  __shared__ ushort_t Bs[2][4096];
  const int t = threadIdx.x;
  const int w = t >> 6;
  const int lane = t & 63;
  const int wr = w >> 1, wc = w & 1;
  const int bm = blockIdx.x * 128, bn = blockIdx.y * 128;

  const int srow = lane >> 2;
  const int scol = (lane & 3) * 8;
  const ushort_t* Ag0 = A + (size_t)(bm + w * 16 + srow) * K + scol;
  const ushort_t* Ag1 = A + (size_t)(bm + 64 + w * 16 + srow) * K + scol;
  const ushort_t* Wg0 = W + (size_t)(bn + w * 16 + srow) * K + scol;
  const ushort_t* Wg1 = W + (size_t)(bn + 64 + w * 16 + srow) * K + scol;
  const int l0 = w * 512;          // ushort offset, issue 0 (rows w*16..+16)
  const int l1 = 2048 + w * 512;   // issue 1 (rows 64+w*16..+16)

  const int lr = lane & 15;
  const int lq = lane >> 4;

  f32x4 acc[4][4];
#pragma unroll
  for (int m = 0; m < 4; m++)
#pragma unroll
    for (int n = 0; n < 4; n++) acc[m][n] = (f32x4)0.f;

  // prologue: stage tile 0 into buf 0
  gload_lds16(Ag0, &As[0][l0]);
  gload_lds16(Ag1, &As[0][l1]);
  gload_lds16(Wg0, &Bs[0][l0]);
  gload_lds16(Wg1, &Bs[0][l1]);
  __syncthreads();   // implicit vmcnt(0) drain

  const int nk = K >> 5;
  int cur = 0;
  for (int kt = 0; kt < nk; kt++) {
    if (kt + 1 < nk) {            // prefetch next tile into other buffer
      const int k1 = (kt + 1) << 5;
      gload_lds16(Ag0 + k1, &As[cur ^ 1][l0]);
      gload_lds16(Ag1 + k1, &As[cur ^ 1][l1]);
      gload_lds16(Wg0 + k1, &Bs[cur ^ 1][l0]);
      gload_lds16(Wg1 + k1, &Bs[cur ^ 1][l1]);
    }
    bf16x8 a[4], b[4];
#pragma unroll
    for (int m = 0; m < 4; m++)
      a[m] = *(const bf16x8*)&As[cur][(wr * 64 + m * 16 + lr) * 32 + lq * 8];
#pragma unroll
    for (int n = 0; n < 4; n++)
      b[n] = *(const bf16x8*)&Bs[cur][(wc * 64 + n * 16 + lr) * 32 + lq * 8];
#pragma unroll
    for (int m = 0; m < 4; m++)
#pragma unroll
      for (int n = 0; n < 4; n++)
        acc[m][n] = __builtin_amdgcn_mfma_f32_16x16x32_bf16(a[m], b[n], acc[m][n], 0, 0, 0);
    __syncthreads();   // lgkmcnt: all reads of buf[cur] done; vmcnt: prefetch landed
    cur ^= 1;
  }

  // epilogue: C/D layout col = lane&15, row = (lane>>4)*4 + r
#pragma unroll
  for (int n = 0; n < 4; n++) {
    const int col = bn + wc * 64 + n * 16 + lr;
    const float bv = bias[col];
#pragma unroll
    for (int m = 0; m < 4; m++) {
      f32x4 v = acc[m][n];
#pragma unroll
      for (int r = 0; r < 4; r++) {
        int row = bm + wr * 64 + m * 16 + lq * 4 + r;
        float u = v[r] + bv;
        if (mode == 1) u = fmaxf(u, 0.f);
        C[(size_t)row * Dout + col] = f2bf(u);
      }
    }
  }
}

// ---------- GRU gates + post-LN (bf16 in, bf16 out, ushort2 loads) ----------
__global__ __launch_bounds__(256) void gate_ln_kernel(
    const ushort_t* __restrict__ Gi, const ushort_t* __restrict__ Gh,
    const ushort_t* __restrict__ Hb, const float* __restrict__ lng,
    const float* __restrict__ lnb, ushort_t* __restrict__ X0) {
  const int token = blockIdx.x;
  const int t = threadIdx.x;
  __shared__ float s_red[4];
  const ushort_t* gi = Gi + (size_t)token * 1536;
  const ushort_t* gh = Gh + (size_t)token * 1536;
  ushort2 gir = *(const ushort2*)&gi[2 * t];
  ushort2 giz = *(const ushort2*)&gi[NG + 2 * t];
  ushort2 gin = *(const ushort2*)&gi[2 * NG + 2 * t];
  ushort2 ghr = *(const ushort2*)&gh[2 * t];
  ushort2 ghz = *(const ushort2*)&gh[NG + 2 * t];
  ushort2 ghn = *(const ushort2*)&gh[2 * NG + 2 * t];
  ushort2 hh = *(const ushort2*)&Hb[(size_t)token * NG + 2 * t];
  float c[2];
  {
    float r0 = 1.f / (1.f + expf(-(bf2f(gir.x) + bf2f(ghr.x))));
    float z0 = 1.f / (1.f + expf(-(bf2f(giz.x) + bf2f(ghz.x))));
    float n0 = tanhf(bf2f(gin.x) + r0 * bf2f(ghn.x));
    c[0] = (1.f - z0) * n0 + z0 * bf2f(hh.x);
    float r1 = 1.f / (1.f + expf(-(bf2f(gir.y) + bf2f(ghr.y))));
    float z1 = 1.f / (1.f + expf(-(bf2f(giz.y) + bf2f(ghz.y))));
    float n1 = tanhf(bf2f(gin.y) + r1 * bf2f(ghn.y));
    c[1] = (1.f - z1) * n1 + z1 * bf2f(hh.y);
  }
  float mean = breduce256(c[0] + c[1], s_red) * (1.0f / NG);
  float d0 = c[0] - mean, d1 = c[1] - mean;
  float var = breduce256(d0 * d0 + d1 * d1, s_red) * (1.0f / NG);
  float rstd = rsqrtf(var + 1e-5f);
  float2 g = *(const float2*)&lng[2 * t];
  float2 be = *(const float2*)&lnb[2 * t];
  ushort2 xo;
  xo.x = f2bf(d0 * rstd * g.x + be.x);
  xo.y = f2bf(d1 * rstd * g.y + be.y);
  *(ushort2*)&X0[(size_t)token * NG + 2 * t] = xo;
}

// ---------- final LN + score (bf16 in) ----------
__global__ __launch_bounds__(256) void ln_score_kernel(
    const ushort_t* __restrict__ X, const float* __restrict__ lng,
    const float* __restrict__ lnb, const float* __restrict__ Wsc,
    const float* __restrict__ bsc, float* __restrict__ scores) {
  const int token = blockIdx.x;
  const int t = threadIdx.x;
  __shared__ float s_red[4];
  ushort2 xx = *(const ushort2*)&X[(size_t)token * ND + 2 * t];
  float v0 = bf2f(xx.x), v1 = bf2f(xx.y);
  float mean = breduce256(v0 + v1, s_red) * (1.0f / ND);
  float d0 = v0 - mean, d1 = v1 - mean;
  float var = breduce256(d0 * d0 + d1 * d1, s_red) * (1.0f / ND);
  float rstd = rsqrtf(var + 1e-5f);
  float2 g = *(const float2*)&lng[2 * t];
  float2 be = *(const float2*)&lnb[2 * t];
  float2 wv = *(const float2*)&Wsc[2 * t];
  float y0 = d0 * rstd * g.x + be.x;
  float y1 = d1 * rstd * g.y + be.y;
  float dot = breduce256(y0 * wv.x + y1 * wv.y, s_red);
  if (t == 0) scores[token] = dot + bsc[0];
}

// ---------- fused softmax + LDS-spectrum scatter (one block per batch) ----------
__global__ __launch_bounds__(256) void softmax_scatter_kernel(
    const float* __restrict__ scores, const int* __restrict__ pidx,
    const float* __restrict__ pint, float* __restrict__ spect,
    float* __restrict__ probs) {
  const int b = blockIdx.x;
  const int t = threadIdx.x;
  __shared__ float s_red[4];
  __shared__ float s_spec[NBINS];
  const float* sc = scores + (size_t)b * NS;
  float v[4];
  float mx = -1e30f;
#pragma unroll
  for (int i = 0; i < 4; i++) { v[i] = sc[t + i * 256]; mx = fmaxf(mx, v[i]); }
#pragma unroll
  for (int off = 32; off > 0; off >>= 1) mx = fmaxf(mx, __shfl_down(mx, off));
  if ((t & 63) == 0) s_red[t >> 6] = mx;
  __syncthreads();
  mx = fmaxf(fmaxf(s_red[0], s_red[1]), fmaxf(s_red[2], s_red[3]));
  float e[4], sum = 0.f;
#pragma unroll
  for (int i = 0; i < 4; i++) { e[i] = expf(v[i] - mx); sum += e[i]; }
  sum = breduce256(sum, s_red);
  float inv = 1.f / sum;
  s_spec[t] = 0.f; s_spec[t + 256] = 0.f;
  float p[4];
#pragma unroll
  for (int i = 0; i < 4; i++) {
    p[i] = e[i] * inv;
    probs[(size_t)b * NS + t + i * 256] = p[i];
  }
  __syncthreads();
#pragma unroll
  for (int i = 0; i < 4; i++) {
    const int s = t + i * 256;
    const int* idx = pidx + ((size_t)b * NS + s) * NM;
    const float* wt = pint + ((size_t)b * NS + s) * NM;
#pragma unroll
    for (int m = 0; m < NM; m++)
      atomicAdd(&s_spec[idx[m]], wt[m] * p[i]);
  }
  __syncthreads();
  spect[(size_t)b * NBINS + t] = s_spec[t];
  spect[(size_t)b * NBINS + t + 256] = s_spec[t + 256];
}

extern "C" void kernel_launch(void* const* d_in, const int* in_sizes, int n_in,
                              void* d_out, int out_size, void* d_ws, size_t ws_size,
                              hipStream_t stream) {
  const float* vert = (const float*)d_in[0];
  const float* mask = (const float*)d_in[1];
  const float* eloh = (const float*)d_in[2];
  const int* subs = (const int*)d_in[3];
  const int* pidx = (const int*)d_in[4];
  const float* pint = (const float*)d_in[5];
  const float* ln_sub_g = (const float*)d_in[6];
  const float* ln_sub_b = (const float*)d_in[7];
  const float* W_ih = (const float*)d_in[8];
  const float* W_hh = (const float*)d_in[9];
  const float* b_ih = (const float*)d_in[10];
  const float* b_hh = (const float*)d_in[11];
  const float* ln_post_g = (const float*)d_in[12];
  const float* ln_post_b = (const float*)d_in[13];
  const float* W1 = (const float*)d_in[14];
  const float* b1 = (const float*)d_in[15];
  const float* W2a = (const float*)d_in[16];
  const float* b2a = (const float*)d_in[17];
  const float* W2b = (const float*)d_in[18];
  const float* b2b = (const float*)d_in[19];
  const float* ln_pre_g = (const float*)d_in[20];
  const float* ln_pre_b = (const float*)d_in[21];
  const float* W_s = (const float*)d_in[22];
  const float* b_s = (const float*)d_in[23];

  float* out = (float*)d_out;            // [0,8192) spect, [8192,24576) probs
  float* probs = out + NB * NBINS;

  // ---- fixed region ----
  char* ws = (char*)d_ws;
  float* scores = (float*)ws;                       // 64 KB
  ushort_t* Wih_bf = (ushort_t*)(ws + 65536);       // 1536*128*2 = 393216
  ushort_t* Whh_bf = (ushort_t*)(ws + 458752);      // 1536*512*2 = 1572864
  ushort_t* W1_bf  = (ushort_t*)(ws + 2031616);     // 512*512*2 = 524288
  ushort_t* W2a_bf = (ushort_t*)(ws + 2555904);
  ushort_t* W2b_bf = (ushort_t*)(ws + 3080192);
  ushort_t* VmT    = (ushort_t*)(ws + 3604480);     // 16*512*32*2 = 524288
  ushort_t* S_bf   = (ushort_t*)(ws + 4128768);     // 16384*32*2 = 1048576
  float*    tcd    = (float*)(ws + 5177344);        // 16384*8*4 = 524288
  const size_t fixed = 5701632;

  // ---- chunked region; per-token bytes:
  //  SWV 2048 | Hb 1024 | F 256 | Gi 3072 | Gh 3072 | X0 1024 = 10496
  const size_t per_tok = 10496;
  int T = NTOK;
  while (T > 1024 && fixed + (size_t)T * per_tok > ws_size) T >>= 1;
  const int nchunks = NTOK / T;

  char* cb = ws + fixed;
  float*    SWV = (float*)cb;                             cb += (size_t)T * 2048;
  ushort_t* Hb  = (ushort_t*)cb;                          cb += (size_t)T * 1024;
  ushort_t* F   = (ushort_t*)cb;                          cb += (size_t)T * 256;
  ushort_t* Gi  = (ushort_t*)cb;                          cb += (size_t)T * 3072;
  ushort_t* Gh  = (ushort_t*)cb;                          cb += (size_t)T * 3072;
  ushort_t* X0  = (ushort_t*)cb;
  ushort_t* X1  = Gi;   // Gi dead after gate_ln
  ushort_t* X2  = Gh;   // Gh dead after gate_ln
  ushort_t* X3  = X0;   // X0 dead after W1 GEMM

  // fused setup: invcnt + 5 weight cvts + VmT prep + S_bf cvt
  const int setup_items = NTOK + 1536 * NFEP + 1536 * NG + 3 * ND * ND
                        + NB * NG * NA + NTOK * NA;
  setup_kernel<<<(setup_items + 255) / 256, 256, 0, stream>>>(
      vert, mask, eloh, subs, W_ih, W_hh, W1, W2a, W2b,
      tcd, Wih_bf, Whh_bf, W1_bf, W2a_bf, W2b_bf, VmT, S_bf);

  for (int c = 0; c < nchunks; c++) {
    const int tok0 = c * T;

    dim3 gp(T / 128, NG / 128);
    pool_gemm<<<gp, 256, 0, stream>>>(S_bf, VmT, tcd, SWV, tok0);
    finish_kernel<<<T, 256, 0, stream>>>(SWV, tcd, ln_sub_g, ln_sub_b, Hb, F, tok0);

    dim3 g1(T / 128, 1536 / 128);
    gemm_bf16<<<g1, 256, 0, stream>>>(F, Wih_bf, b_ih, Gi, NFEP, 1536, 3);
    gemm_bf16<<<g1, 256, 0, stream>>>(Hb, Whh_bf, b_hh, Gh, NG, 1536, 3);

    gate_ln_kernel<<<T, 256, 0, stream>>>(Gi, Gh, Hb, ln_post_g, ln_post_b, X0);

    dim3 g2(T / 128, ND / 128);
    gemm_bf16<<<g2, 256, 0, stream>>>(X0, W1_bf, b1, X1, NG, ND, 1);
    gemm_bf16<<<g2, 256, 0, stream>>>(X1, W2a_bf, b2a, X2, ND, ND, 1);
    gemm_bf16<<<g2, 256, 0, stream>>>(X2, W2b_bf, b2b, X3, ND, ND, 1);

    ln_score_kernel<<<T, 256, 0, stream>>>(X3, ln_pre_g, ln_pre_b, W_s, b_s, scores + tok0);
  }

  softmax_scatter_kernel<<<NB, 256, 0, stream>>>(scores, pidx, pint, out, probs);
}

// Round 7
// 270.246 us; speedup vs baseline: 3.8766x; 1.1141x over previous
//
#include <hip/hip_runtime.h>

#define NB 16
#define NA 32
#define NG 512
#define NS 1024
#define NM 8
#define NE 5
#define NOH 20
#define NFE 100
#define ND 512
#define NBINS 512
#define NTOK (NB * NS)

typedef unsigned short ushort_t;
typedef __attribute__((ext_vector_type(8))) short bf16x8;
typedef __attribute__((ext_vector_type(4))) float f32x4;

__device__ __forceinline__ ushort_t f2bf(float x) {
  union { float f; unsigned u; } v; v.f = x;
  unsigned r = v.u + 0x7FFF + ((v.u >> 16) & 1);   // RNE
  return (ushort_t)(r >> 16);
}
__device__ __forceinline__ float bf2f(ushort_t b) {
  union { unsigned u; float f; } v; v.u = ((unsigned)b) << 16;
  return v.f;
}

__device__ __forceinline__ void gload_lds16(const void* g, void* l) {
  __builtin_amdgcn_global_load_lds(
      (const __attribute__((address_space(1))) void*)g,
      (__attribute__((address_space(3))) void*)l, 16, 0, 0);
}

// wave-wide (64 lanes) butterfly sum; all lanes get result
__device__ __forceinline__ float wsum64(float v) {
#pragma unroll
  for (int off = 32; off > 0; off >>= 1) v += __shfl_xor(v, off);
  return v;
}

// ---------- fused setup: invcnt | PS prefix table | weight cvt | VmT | S_bf ----------
__global__ __launch_bounds__(256) void setup_kernel(
    const float* __restrict__ vert, const float* __restrict__ mask,
    const float* __restrict__ eloh, const int* __restrict__ subs,
    const float* __restrict__ Wih, const float* __restrict__ Whh,
    const float* __restrict__ W1, const float* __restrict__ W2a,
    const float* __restrict__ W2b,
    float* __restrict__ tcd, float* __restrict__ PS,
    ushort_t* __restrict__ o_hh, ushort_t* __restrict__ o1,
    ushort_t* __restrict__ o2a, ushort_t* __restrict__ o2b,
    ushort_t* __restrict__ VmT, ushort_t* __restrict__ S_bf) {
  int i = blockIdx.x * 256 + threadIdx.x;
  if (i < NTOK) {   // per-token subset-size inverse + element counts (fp32 exact)
    int b = i >> 10;
    const int* srow = subs + (size_t)i * NA;
    float cnt[NE] = {0.f, 0.f, 0.f, 0.f, 0.f};
    float z = 0.f;
    for (int a = 0; a < NA; a++) {
      float sb = (float)srow[a];
      z += sb * mask[b * NA + a];
      const float* eo = eloh + (size_t)(b * NA + a) * NE;
#pragma unroll
      for (int e = 0; e < NE; e++) cnt[e] += eo[e] * sb;
    }
    float* o = tcd + (size_t)i * 8;
#pragma unroll
    for (int e = 0; e < NE; e++) o[e] = cnt[e];
    o[5] = 1.0f / (z + 1e-4f);
    return;
  }
  i -= NTOK;
  if (i < NE * 1536) {   // PS[e][c][g] = sum_{o<c} W_ih[g][e*20+o], fp32 exact
    int e = i / 1536, g = i % 1536;
    float s = 0.f;
    float* base = PS + ((size_t)e * 21) * 1536 + g;
    base[0] = 0.f;
    for (int c = 1; c <= NOH; c++) {
      s += Wih[(size_t)g * NFE + e * NOH + (c - 1)];
      base[(size_t)c * 1536] = s;
    }
    return;
  }
  i -= NE * 1536;
  if (i < 1536 * NG) { o_hh[i] = f2bf(Whh[i]); return; }
  i -= 1536 * NG;
  if (i < ND * NG) { o1[i] = f2bf(W1[i]); return; }
  i -= ND * NG;
  if (i < ND * ND) { o2a[i] = f2bf(W2a[i]); return; }
  i -= ND * ND;
  if (i < ND * ND) { o2b[i] = f2bf(W2b[i]); return; }
  i -= ND * ND;
  const int nV = NB * NG * NA;
  if (i < nV) {   // VmT[b][f][a] = bf16(vert*mask^2)
    int b = i / (NG * NA); int rem = i % (NG * NA);
    int f = rem >> 5, a = rem & 31;
    float mk = mask[b * NA + a];
    VmT[i] = f2bf(vert[(size_t)b * NA * NG + a * NG + f] * mk * mk);
    return;
  }
  i -= nV;
  if (i < NTOK * NA) S_bf[i] = f2bf((float)subs[i]);   // 0/1 exact
}

// ---------- pool GEMM: SWV[ltok][f] = (subs @ VmT^T) * inv  (K=32, one MFMA step) ----------
__global__ __launch_bounds__(256) void pool_gemm(
    const ushort_t* __restrict__ S_bf, const ushort_t* __restrict__ VmT,
    const float* __restrict__ tcd, float* __restrict__ SWV, int tok0) {
  __shared__ ushort_t As[128 * 32];
  __shared__ ushort_t Bs[128 * 32];
  const int t = threadIdx.x;
  const int w = t >> 6, lane = t & 63;
  const int wr = w >> 1, wc = w & 1;
  const int bm = blockIdx.x * 128;   // chunk-local token base
  const int bn = blockIdx.y * 128;   // f base
  const int b = (tok0 + bm) >> 10;   // 128 | 1024 so tile is single-batch
  const int srow = lane >> 2;
  const int scol = (((lane & 3) ^ ((lane >> 3) & 3)) * 8);   // pre-swizzled source chunk
  const ushort_t* Bbase = VmT + (size_t)b * NG * NA;
  gload_lds16(S_bf + (size_t)(tok0 + bm + w * 16 + srow) * 32 + scol, &As[w * 512]);
  gload_lds16(S_bf + (size_t)(tok0 + bm + 64 + w * 16 + srow) * 32 + scol, &As[2048 + w * 512]);
  gload_lds16(Bbase + (size_t)(bn + w * 16 + srow) * 32 + scol, &Bs[w * 512]);
  gload_lds16(Bbase + (size_t)(bn + 64 + w * 16 + srow) * 32 + scol, &Bs[2048 + w * 512]);
  __syncthreads();

  const int lr = lane & 15, lq = lane >> 4;
  const int rchunk = (lq ^ ((lr >> 1) & 3)) * 8;   // swizzled read chunk
  f32x4 acc[4][4];
#pragma unroll
  for (int m = 0; m < 4; m++)
#pragma unroll
    for (int n = 0; n < 4; n++) acc[m][n] = (f32x4)0.f;
  bf16x8 a[4], bb[4];
#pragma unroll
  for (int m = 0; m < 4; m++)
    a[m] = *(const bf16x8*)&As[(wr * 64 + m * 16 + lr) * 32 + rchunk];
#pragma unroll
  for (int n = 0; n < 4; n++)
    bb[n] = *(const bf16x8*)&Bs[(wc * 64 + n * 16 + lr) * 32 + rchunk];
#pragma unroll
  for (int m = 0; m < 4; m++)
#pragma unroll
    for (int n = 0; n < 4; n++)
      acc[m][n] = __builtin_amdgcn_mfma_f32_16x16x32_bf16(a[m], bb[n], acc[m][n], 0, 0, 0);

#pragma unroll
  for (int n = 0; n < 4; n++) {
    const int col = bn + wc * 64 + n * 16 + lr;
#pragma unroll
    for (int m = 0; m < 4; m++) {
      f32x4 v = acc[m][n];
#pragma unroll
      for (int r = 0; r < 4; r++) {
        int row = bm + wr * 64 + m * 16 + lq * 4 + r;
        float inv = tcd[(size_t)(tok0 + row) * 8 + 5];
        SWV[(size_t)row * NG + col] = v[r] * inv;
      }
    }
  }
}

// ---------- finish: LN(swv_mean) -> Hb bf16 (wave per token, 4 tokens/block) ----------
__global__ __launch_bounds__(256) void finish_kernel(
    const float* __restrict__ SWV, const float* __restrict__ lng,
    const float* __restrict__ lnb, ushort_t* __restrict__ Hb) {
  const int t = threadIdx.x;
  const int lane = t & 63, wv = t >> 6;
  const int ltok = blockIdx.x * 4 + wv;
  const int f = lane * 8;
  const float* row = SWV + (size_t)ltok * NG + f;
  float4 v0 = *(const float4*)row;
  float4 v1 = *(const float4*)(row + 4);
  float x[8] = {v0.x, v0.y, v0.z, v0.w, v1.x, v1.y, v1.z, v1.w};
  float ps = 0.f;
#pragma unroll
  for (int j = 0; j < 8; j++) ps += x[j];
  float mean = wsum64(ps) * (1.0f / NG);
  float pq = 0.f;
#pragma unroll
  for (int j = 0; j < 8; j++) { float d = x[j] - mean; pq += d * d; }
  float rstd = rsqrtf(wsum64(pq) * (1.0f / NG) + 1e-5f);
  float4 g0 = *(const float4*)&lng[f], g1 = *(const float4*)&lng[f + 4];
  float4 b0 = *(const float4*)&lnb[f], b1 = *(const float4*)&lnb[f + 4];
  float gg[8] = {g0.x, g0.y, g0.z, g0.w, g1.x, g1.y, g1.z, g1.w};
  float bbv[8] = {b0.x, b0.y, b0.z, b0.w, b1.x, b1.y, b1.z, b1.w};
  bf16x8 ho;
#pragma unroll
  for (int j = 0; j < 8; j++) ho[j] = (short)f2bf((x[j] - mean) * rstd * gg[j] + bbv[j]);
  *(bf16x8*)&Hb[(size_t)ltok * NG + f] = ho;
}

// ---------- bf16 MFMA GEMM, double-buffered prefetch + swizzled LDS ----------
// BM=BN=128, BK=32, 4 waves (2x2), 4x4 16x16x32 frags per wave
// mode: 1 = bf16 out relu, 3 = bf16 out no act
__global__ __launch_bounds__(256) void gemm_bf16(
    const ushort_t* __restrict__ A, const ushort_t* __restrict__ W,
    const float* __restrict__ bias, ushort_t* __restrict__ C,
    int K, int Dout, int mode) {
  __shared__ ushort_t As[2][4096];
  __shared__ ushort_t Bs[2][4096];
  const int t = threadIdx.x;
  const int w = t >> 6;
  const int lane = t & 63;
  const int wr = w >> 1, wc = w & 1;
  const int bm = blockIdx.x * 128, bn = blockIdx.y * 128;

  const int srow = lane >> 2;
  const int scol = (((lane & 3) ^ ((lane >> 3) & 3)) * 8);   // pre-swizzled source chunk
  const ushort_t* Ag0 = A + (size_t)(bm + w * 16 + srow) * K + scol;
  const ushort_t* Ag1 = A + (size_t)(bm + 64 + w * 16 + srow) * K + scol;
  const ushort_t* Wg0 = W + (size_t)(bn + w * 16 + srow) * K + scol;
  const ushort_t* Wg1 = W + (size_t)(bn + 64 + w * 16 + srow) * K + scol;
  const int l0 = w * 512;          // ushort offset, issue 0 (rows w*16..+16)
  const int l1 = 2048 + w * 512;   // issue 1 (rows 64+w*16..+16)

  const int lr = lane & 15;
  const int lq = lane >> 4;
  const int rchunk = (lq ^ ((lr >> 1) & 3)) * 8;   // swizzled read chunk

  f32x4 acc[4][4];
#pragma unroll
  for (int m = 0; m < 4; m++)
#pragma unroll
    for (int n = 0; n < 4; n++) acc[m][n] = (f32x4)0.f;

  // prologue: stage tile 0 into buf 0
  gload_lds16(Ag0, &As[0][l0]);
  gload_lds16(Ag1, &As[0][l1]);
  gload_lds16(Wg0, &Bs[0][l0]);
  gload_lds16(Wg1, &Bs[0][l1]);
  __syncthreads();

  const int nk = K >> 5;
  int cur = 0;
  for (int kt = 0; kt < nk; kt++) {
    if (kt + 1 < nk) {            // prefetch next tile into other buffer
      const int k1 = (kt + 1) << 5;
      gload_lds16(Ag0 + k1, &As[cur ^ 1][l0]);
      gload_lds16(Ag1 + k1, &As[cur ^ 1][l1]);
      gload_lds16(Wg0 + k1, &Bs[cur ^ 1][l0]);
      gload_lds16(Wg1 + k1, &Bs[cur ^ 1][l1]);
    }
    bf16x8 a[4], b[4];
#pragma unroll
    for (int m = 0; m < 4; m++)
      a[m] = *(const bf16x8*)&As[cur][(wr * 64 + m * 16 + lr) * 32 + rchunk];
#pragma unroll
    for (int n = 0; n < 4; n++)
      b[n] = *(const bf16x8*)&Bs[cur][(wc * 64 + n * 16 + lr) * 32 + rchunk];
#pragma unroll
    for (int m = 0; m < 4; m++)
#pragma unroll
      for (int n = 0; n < 4; n++)
        acc[m][n] = __builtin_amdgcn_mfma_f32_16x16x32_bf16(a[m], b[n], acc[m][n], 0, 0, 0);
    __syncthreads();   // drains lgkm (buf reads) and vm (prefetch) before swap
    cur ^= 1;
  }

  // epilogue: C/D layout col = lane&15, row = (lane>>4)*4 + r
#pragma unroll
  for (int n = 0; n < 4; n++) {
    const int col = bn + wc * 64 + n * 16 + lr;
    const float bv = bias[col];
#pragma unroll
    for (int m = 0; m < 4; m++) {
      f32x4 v = acc[m][n];
#pragma unroll
      for (int r = 0; r < 4; r++) {
        int row = bm + wr * 64 + m * 16 + lq * 4 + r;
        float u = v[r] + bv;
        if (mode == 1) u = fmaxf(u, 0.f);
        C[(size_t)row * Dout + col] = f2bf(u);
      }
    }
  }
}

// ---------- GRU gates + post-LN, gi via PS gather (wave per token) ----------
__global__ __launch_bounds__(256) void gate_ln_kernel(
    const ushort_t* __restrict__ Gh, const ushort_t* __restrict__ Hb,
    const float* __restrict__ tcd, const float* __restrict__ PS,
    const float* __restrict__ b_ih, const float* __restrict__ lng,
    const float* __restrict__ lnb, ushort_t* __restrict__ X0) {
  const int t = threadIdx.x;
  const int lane = t & 63, wv = t >> 6;
  const int ltok = blockIdx.x * 4 + wv;
  const int f = lane * 8;
  int c[NE];
#pragma unroll
  for (int e = 0; e < NE; e++) {
    int ci = (int)tcd[(size_t)ltok * 8 + e];   // exact integer-valued fp32
    c[e] = ci > NOH ? NOH : ci;
  }
  float4 r0 = *(const float4*)&b_ih[f],          r1 = *(const float4*)&b_ih[f + 4];
  float4 z0 = *(const float4*)&b_ih[NG + f],     z1 = *(const float4*)&b_ih[NG + f + 4];
  float4 n0 = *(const float4*)&b_ih[2 * NG + f], n1 = *(const float4*)&b_ih[2 * NG + f + 4];
#pragma unroll
  for (int e = 0; e < NE; e++) {
    const float* pe = PS + ((size_t)(e * 21 + c[e])) * 1536;
    r0 += *(const float4*)&pe[f];          r1 += *(const float4*)&pe[f + 4];
    z0 += *(const float4*)&pe[NG + f];     z1 += *(const float4*)&pe[NG + f + 4];
    n0 += *(const float4*)&pe[2 * NG + f]; n1 += *(const float4*)&pe[2 * NG + f + 4];
  }
  float gir[8] = {r0.x, r0.y, r0.z, r0.w, r1.x, r1.y, r1.z, r1.w};
  float giz[8] = {z0.x, z0.y, z0.z, z0.w, z1.x, z1.y, z1.z, z1.w};
  float gin[8] = {n0.x, n0.y, n0.z, n0.w, n1.x, n1.y, n1.z, n1.w};

  const ushort_t* gh = Gh + (size_t)ltok * 1536;
  bf16x8 vr = *(const bf16x8*)&gh[f];
  bf16x8 vz = *(const bf16x8*)&gh[NG + f];
  bf16x8 vn = *(const bf16x8*)&gh[2 * NG + f];
  bf16x8 vh = *(const bf16x8*)&Hb[(size_t)ltok * NG + f];
  float cv[8];
  float ps = 0.f;
#pragma unroll
  for (int j = 0; j < 8; j++) {
    float rg = 1.f / (1.f + expf(-(gir[j] + bf2f((ushort_t)vr[j]))));
    float zg = 1.f / (1.f + expf(-(giz[j] + bf2f((ushort_t)vz[j]))));
    float ng = tanhf(gin[j] + rg * bf2f((ushort_t)vn[j]));
    cv[j] = (1.f - zg) * ng + zg * bf2f((ushort_t)vh[j]);
    ps += cv[j];
  }
  float mean = wsum64(ps) * (1.0f / NG);
  float pq = 0.f;
#pragma unroll
  for (int j = 0; j < 8; j++) { float d = cv[j] - mean; pq += d * d; }
  float rstd = rsqrtf(wsum64(pq) * (1.0f / NG) + 1e-5f);
  float4 g0 = *(const float4*)&lng[f], g1 = *(const float4*)&lng[f + 4];
  float4 b0 = *(const float4*)&lnb[f], b1 = *(const float4*)&lnb[f + 4];
  float gg[8] = {g0.x, g0.y, g0.z, g0.w, g1.x, g1.y, g1.z, g1.w};
  float bbv[8] = {b0.x, b0.y, b0.z, b0.w, b1.x, b1.y, b1.z, b1.w};
  bf16x8 xo;
#pragma unroll
  for (int j = 0; j < 8; j++) xo[j] = (short)f2bf((cv[j] - mean) * rstd * gg[j] + bbv[j]);
  *(bf16x8*)&X0[(size_t)ltok * NG + f] = xo;
}

// ---------- final LN + score (wave per token) ----------
__global__ __launch_bounds__(256) void ln_score_kernel(
    const ushort_t* __restrict__ X, const float* __restrict__ lng,
    const float* __restrict__ lnb, const float* __restrict__ Wsc,
    const float* __restrict__ bsc, float* __restrict__ scores) {
  const int t = threadIdx.x;
  const int lane = t & 63, wv = t >> 6;
  const int ltok = blockIdx.x * 4 + wv;
  const int f = lane * 8;
  bf16x8 xx = *(const bf16x8*)&X[(size_t)ltok * ND + f];
  float x[8];
  float ps = 0.f;
#pragma unroll
  for (int j = 0; j < 8; j++) { x[j] = bf2f((ushort_t)xx[j]); ps += x[j]; }
  float mean = wsum64(ps) * (1.0f / ND);
  float pq = 0.f;
#pragma unroll
  for (int j = 0; j < 8; j++) { float d = x[j] - mean; pq += d * d; }
  float rstd = rsqrtf(wsum64(pq) * (1.0f / ND) + 1e-5f);
  float4 g0 = *(const float4*)&lng[f], g1 = *(const float4*)&lng[f + 4];
  float4 b0 = *(const float4*)&lnb[f], b1 = *(const float4*)&lnb[f + 4];
  float4 w0 = *(const float4*)&Wsc[f], w1 = *(const float4*)&Wsc[f + 4];
  float gg[8] = {g0.x, g0.y, g0.z, g0.w, g1.x, g1.y, g1.z, g1.w};
  float bbv[8] = {b0.x, b0.y, b0.z, b0.w, b1.x, b1.y, b1.z, b1.w};
  float ww[8] = {w0.x, w0.y, w0.z, w0.w, w1.x, w1.y, w1.z, w1.w};
  float d = 0.f;
#pragma unroll
  for (int j = 0; j < 8; j++) d += ((x[j] - mean) * rstd * gg[j] + bbv[j]) * ww[j];
  float dot = wsum64(d);
  if (lane == 0) scores[ltok] = dot + bsc[0];
}

// ---------- fused softmax + LDS-spectrum scatter (one block per batch) ----------
__global__ __launch_bounds__(256) void softmax_scatter_kernel(
    const float* __restrict__ scores, const int* __restrict__ pidx,
    const float* __restrict__ pint, float* __restrict__ spect,
    float* __restrict__ probs) {
  const int b = blockIdx.x;
  const int t = threadIdx.x;
  __shared__ float s_red[4];
  __shared__ float s_spec[NBINS];
  const float* sc = scores + (size_t)b * NS;
  float v[4];
  float mx = -1e30f;
#pragma unroll
  for (int i = 0; i < 4; i++) { v[i] = sc[t + i * 256]; mx = fmaxf(mx, v[i]); }
#pragma unroll
  for (int off = 32; off > 0; off >>= 1) mx = fmaxf(mx, __shfl_down(mx, off));
  if ((t & 63) == 0) s_red[t >> 6] = mx;
  __syncthreads();
  mx = fmaxf(fmaxf(s_red[0], s_red[1]), fmaxf(s_red[2], s_red[3]));
  float e[4], sum = 0.f;
#pragma unroll
  for (int i = 0; i < 4; i++) { e[i] = expf(v[i] - mx); sum += e[i]; }
#pragma unroll
  for (int off = 32; off > 0; off >>= 1) sum += __shfl_down(sum, off);
  __syncthreads();
  if ((t & 63) == 0) s_red[t >> 6] = sum;
  __syncthreads();
  sum = s_red[0] + s_red[1] + s_red[2] + s_red[3];
  float inv = 1.f / sum;
  s_spec[t] = 0.f; s_spec[t + 256] = 0.f;
  float p[4];
#pragma unroll
  for (int i = 0; i < 4; i++) {
    p[i] = e[i] * inv;
    probs[(size_t)b * NS + t + i * 256] = p[i];
  }
  __syncthreads();
#pragma unroll
  for (int i = 0; i < 4; i++) {
    const int s = t + i * 256;
    const int* idx = pidx + ((size_t)b * NS + s) * NM;
    const float* wt = pint + ((size_t)b * NS + s) * NM;
#pragma unroll
    for (int m = 0; m < NM; m++)
      atomicAdd(&s_spec[idx[m]], wt[m] * p[i]);
  }
  __syncthreads();
  spect[(size_t)b * NBINS + t] = s_spec[t];
  spect[(size_t)b * NBINS + t + 256] = s_spec[t + 256];
}

extern "C" void kernel_launch(void* const* d_in, const int* in_sizes, int n_in,
                              void* d_out, int out_size, void* d_ws, size_t ws_size,
                              hipStream_t stream) {
  const float* vert = (const float*)d_in[0];
  const float* mask = (const float*)d_in[1];
  const float* eloh = (const float*)d_in[2];
  const int* subs = (const int*)d_in[3];
  const int* pidx = (const int*)d_in[4];
  const float* pint = (const float*)d_in[5];
  const float* ln_sub_g = (const float*)d_in[6];
  const float* ln_sub_b = (const float*)d_in[7];
  const float* W_ih = (const float*)d_in[8];
  const float* W_hh = (const float*)d_in[9];
  const float* b_ih = (const float*)d_in[10];
  const float* b_hh = (const float*)d_in[11];
  const float* ln_post_g = (const float*)d_in[12];
  const float* ln_post_b = (const float*)d_in[13];
  const float* W1 = (const float*)d_in[14];
  const float* b1 = (const float*)d_in[15];
  const float* W2a = (const float*)d_in[16];
  const float* b2a = (const float*)d_in[17];
  const float* W2b = (const float*)d_in[18];
  const float* b2b = (const float*)d_in[19];
  const float* ln_pre_g = (const float*)d_in[20];
  const float* ln_pre_b = (const float*)d_in[21];
  const float* W_s = (const float*)d_in[22];
  const float* b_s = (const float*)d_in[23];

  float* out = (float*)d_out;            // [0,8192) spect, [8192,24576) probs
  float* probs = out + NB * NBINS;

  // ---- fixed region ----
  char* ws = (char*)d_ws;
  float* scores = (float*)ws;                       // 64 KB
  ushort_t* Whh_bf = (ushort_t*)(ws + 65536);       // 1536*512*2 = 1572864
  ushort_t* W1_bf  = (ushort_t*)(ws + 1638400);     // 512*512*2 = 524288
  ushort_t* W2a_bf = (ushort_t*)(ws + 2162688);
  ushort_t* W2b_bf = (ushort_t*)(ws + 2686976);
  ushort_t* VmT    = (ushort_t*)(ws + 3211264);     // 16*512*32*2 = 524288
  ushort_t* S_bf   = (ushort_t*)(ws + 3735552);     // 16384*32*2 = 1048576
  float*    tcd    = (float*)(ws + 4784128);        // 16384*8*4 = 524288
  float*    PS     = (float*)(ws + 5308416);        // 5*21*1536*4 = 645120
  const size_t fixed = 5953536;

  // ---- chunked region; per-token bytes: SWV 2048 | Hb 1024 | Gh 3072 | X0 1024 = 7168
  const size_t per_tok = 7168;
  int T = NTOK;
  while (T > 1024 && fixed + (size_t)T * per_tok > ws_size) T >>= 1;
  const int nchunks = NTOK / T;

  char* cb = ws + fixed;
  float*    SWV = (float*)cb;                             cb += (size_t)T * 2048;
  ushort_t* Hb  = (ushort_t*)cb;                          cb += (size_t)T * 1024;
  ushort_t* Gh  = (ushort_t*)cb;                          cb += (size_t)T * 3072;
  ushort_t* X0  = (ushort_t*)cb;
  ushort_t* X1  = Gh;                  // Gh dead after gate_ln
  ushort_t* X2  = Gh + (size_t)T * 512;
  ushort_t* X3  = X0;                  // X0 dead after W1 GEMM

  // fused setup: invcnt + PS prefix table + 4 weight cvts + VmT prep + S_bf cvt
  const int setup_items = NTOK + NE * 1536 + 1536 * NG + ND * NG + 2 * ND * ND
                        + NB * NG * NA + NTOK * NA;
  setup_kernel<<<(setup_items + 255) / 256, 256, 0, stream>>>(
      vert, mask, eloh, subs, W_ih, W_hh, W1, W2a, W2b,
      tcd, PS, Whh_bf, W1_bf, W2a_bf, W2b_bf, VmT, S_bf);

  for (int c = 0; c < nchunks; c++) {
    const int tok0 = c * T;

    dim3 gp(T / 128, NG / 128);
    pool_gemm<<<gp, 256, 0, stream>>>(S_bf, VmT, tcd, SWV, tok0);
    finish_kernel<<<T / 4, 256, 0, stream>>>(SWV, ln_sub_g, ln_sub_b, Hb);

    dim3 g1(T / 128, 1536 / 128);
    gemm_bf16<<<g1, 256, 0, stream>>>(Hb, Whh_bf, b_hh, Gh, NG, 1536, 3);

    gate_ln_kernel<<<T / 4, 256, 0, stream>>>(Gh, Hb, tcd + (size_t)tok0 * 8, PS,
                                              b_ih, ln_post_g, ln_post_b, X0);

    dim3 g2(T / 128, ND / 128);
    gemm_bf16<<<g2, 256, 0, stream>>>(X0, W1_bf, b1, X1, NG, ND, 1);
    gemm_bf16<<<g2, 256, 0, stream>>>(X1, W2a_bf, b2a, X2, ND, ND, 1);
    gemm_bf16<<<g2, 256, 0, stream>>>(X2, W2b_bf, b2b, X3, ND, ND, 1);

    ln_score_kernel<<<T / 4, 256, 0, stream>>>(X3, ln_pre_g, ln_pre_b, W_s, b_s,
                                               scores + tok0);
  }

  softmax_scatter_kernel<<<NB, 256, 0, stream>>>(scores, pidx, pint, out, probs);
}

// Round 8
// 269.253 us; speedup vs baseline: 3.8909x; 1.0037x over previous
//
#include <hip/hip_runtime.h>

#define NB 16
#define NA 32
#define NG 512
#define NS 1024
#define NM 8
#define NE 5
#define NOH 20
#define NFE 100
#define ND 512
#define NBINS 512
#define NTOK (NB * NS)

typedef unsigned short ushort_t;
typedef __attribute__((ext_vector_type(8))) short bf16x8;
typedef __attribute__((ext_vector_type(4))) float f32x4;

__device__ __forceinline__ ushort_t f2bf(float x) {
  union { float f; unsigned u; } v; v.f = x;
  unsigned r = v.u + 0x7FFF + ((v.u >> 16) & 1);   // RNE
  return (ushort_t)(r >> 16);
}
__device__ __forceinline__ float bf2f(ushort_t b) {
  union { unsigned u; float f; } v; v.u = ((unsigned)b) << 16;
  return v.f;
}

__device__ __forceinline__ void gload_lds16(const void* g, void* l) {
  __builtin_amdgcn_global_load_lds(
      (const __attribute__((address_space(1))) void*)g,
      (__attribute__((address_space(3))) void*)l, 16, 0, 0);
}

// wave-wide (64 lanes) butterfly sum; all lanes get result
__device__ __forceinline__ float wsum64(float v) {
#pragma unroll
  for (int off = 32; off > 0; off >>= 1) v += __shfl_xor(v, off);
  return v;
}

// ---------- fused setup: invcnt | PS prefix table | weight cvt | VmT | S_bf ----------
__global__ __launch_bounds__(256) void setup_kernel(
    const float* __restrict__ vert, const float* __restrict__ mask,
    const float* __restrict__ eloh, const int* __restrict__ subs,
    const float* __restrict__ Wih, const float* __restrict__ Whh,
    const float* __restrict__ W1, const float* __restrict__ W2a,
    const float* __restrict__ W2b,
    float* __restrict__ tcd, float* __restrict__ PS,
    ushort_t* __restrict__ o_hh, ushort_t* __restrict__ o1,
    ushort_t* __restrict__ o2a, ushort_t* __restrict__ o2b,
    ushort_t* __restrict__ VmT, ushort_t* __restrict__ S_bf) {
  int i = blockIdx.x * 256 + threadIdx.x;
  if (i < NTOK) {   // per-token subset-size inverse + element counts (fp32 exact)
    int b = i >> 10;
    const int* srow = subs + (size_t)i * NA;
    float cnt[NE] = {0.f, 0.f, 0.f, 0.f, 0.f};
    float z = 0.f;
    for (int a = 0; a < NA; a++) {
      float sb = (float)srow[a];
      z += sb * mask[b * NA + a];
      const float* eo = eloh + (size_t)(b * NA + a) * NE;
#pragma unroll
      for (int e = 0; e < NE; e++) cnt[e] += eo[e] * sb;
    }
    float* o = tcd + (size_t)i * 8;
#pragma unroll
    for (int e = 0; e < NE; e++) o[e] = cnt[e];
    o[5] = 1.0f / (z + 1e-4f);
    return;
  }
  i -= NTOK;
  if (i < NE * 1536) {   // PS[e][c][g] = sum_{o<c} W_ih[g][e*20+o], fp32 exact
    int e = i / 1536, g = i % 1536;
    float s = 0.f;
    float* base = PS + ((size_t)e * 21) * 1536 + g;
    base[0] = 0.f;
    for (int c = 1; c <= NOH; c++) {
      s += Wih[(size_t)g * NFE + e * NOH + (c - 1)];
      base[(size_t)c * 1536] = s;
    }
    return;
  }
  i -= NE * 1536;
  if (i < 1536 * NG) { o_hh[i] = f2bf(Whh[i]); return; }
  i -= 1536 * NG;
  if (i < ND * NG) { o1[i] = f2bf(W1[i]); return; }
  i -= ND * NG;
  if (i < ND * ND) { o2a[i] = f2bf(W2a[i]); return; }
  i -= ND * ND;
  if (i < ND * ND) { o2b[i] = f2bf(W2b[i]); return; }
  i -= ND * ND;
  const int nV = NB * NG * NA;
  if (i < nV) {   // VmT[b][f][a] = bf16(vert*mask^2)
    int b = i / (NG * NA); int rem = i % (NG * NA);
    int f = rem >> 5, a = rem & 31;
    float mk = mask[b * NA + a];
    VmT[i] = f2bf(vert[(size_t)b * NA * NG + a * NG + f] * mk * mk);
    return;
  }
  i -= nV;
  if (i < NTOK * NA) S_bf[i] = f2bf((float)subs[i]);   // 0/1 exact
}

// ---------- pool GEMM: SWV[ltok][f] = (subs @ VmT^T) * inv  (K=32, one MFMA step) ----------
__global__ __launch_bounds__(256) void pool_gemm(
    const ushort_t* __restrict__ S_bf, const ushort_t* __restrict__ VmT,
    const float* __restrict__ tcd, float* __restrict__ SWV, int tok0) {
  __shared__ ushort_t As[128 * 32];
  __shared__ ushort_t Bs[128 * 32];
  const int t = threadIdx.x;
  const int w = t >> 6, lane = t & 63;
  const int wr = w >> 1, wc = w & 1;
  const int bm = blockIdx.x * 128;   // chunk-local token base
  const int bn = blockIdx.y * 128;   // f base
  const int b = (tok0 + bm) >> 10;   // 128 | 1024 so tile is single-batch
  const int srow = lane >> 2;
  const int scol = (((lane & 3) ^ ((lane >> 3) & 3)) * 8);   // pre-swizzled source chunk
  const ushort_t* Bbase = VmT + (size_t)b * NG * NA;
  gload_lds16(S_bf + (size_t)(tok0 + bm + w * 16 + srow) * 32 + scol, &As[w * 512]);
  gload_lds16(S_bf + (size_t)(tok0 + bm + 64 + w * 16 + srow) * 32 + scol, &As[2048 + w * 512]);
  gload_lds16(Bbase + (size_t)(bn + w * 16 + srow) * 32 + scol, &Bs[w * 512]);
  gload_lds16(Bbase + (size_t)(bn + 64 + w * 16 + srow) * 32 + scol, &Bs[2048 + w * 512]);
  __syncthreads();

  const int lr = lane & 15, lq = lane >> 4;
  const int rchunk = (lq ^ ((lr >> 1) & 3)) * 8;   // swizzled read chunk
  f32x4 acc[4][4];
#pragma unroll
  for (int m = 0; m < 4; m++)
#pragma unroll
    for (int n = 0; n < 4; n++) acc[m][n] = (f32x4)0.f;
  bf16x8 a[4], bb[4];
#pragma unroll
  for (int m = 0; m < 4; m++)
    a[m] = *(const bf16x8*)&As[(wr * 64 + m * 16 + lr) * 32 + rchunk];
#pragma unroll
  for (int n = 0; n < 4; n++)
    bb[n] = *(const bf16x8*)&Bs[(wc * 64 + n * 16 + lr) * 32 + rchunk];
#pragma unroll
  for (int m = 0; m < 4; m++)
#pragma unroll
    for (int n = 0; n < 4; n++)
      acc[m][n] = __builtin_amdgcn_mfma_f32_16x16x32_bf16(a[m], bb[n], acc[m][n], 0, 0, 0);

#pragma unroll
  for (int n = 0; n < 4; n++) {
    const int col = bn + wc * 64 + n * 16 + lr;
#pragma unroll
    for (int m = 0; m < 4; m++) {
      f32x4 v = acc[m][n];
#pragma unroll
      for (int r = 0; r < 4; r++) {
        int row = bm + wr * 64 + m * 16 + lq * 4 + r;
        float inv = tcd[(size_t)(tok0 + row) * 8 + 5];
        SWV[(size_t)row * NG + col] = v[r] * inv;
      }
    }
  }
}

// ---------- finish: LN(swv_mean) -> Hb bf16 (wave per token, 4 tokens/block) ----------
__global__ __launch_bounds__(256) void finish_kernel(
    const float* __restrict__ SWV, const float* __restrict__ lng,
    const float* __restrict__ lnb, ushort_t* __restrict__ Hb) {
  const int t = threadIdx.x;
  const int lane = t & 63, wv = t >> 6;
  const int ltok = blockIdx.x * 4 + wv;
  const int f = lane * 8;
  const float* row = SWV + (size_t)ltok * NG + f;
  float4 v0 = *(const float4*)row;
  float4 v1 = *(const float4*)(row + 4);
  float x[8] = {v0.x, v0.y, v0.z, v0.w, v1.x, v1.y, v1.z, v1.w};
  float ps = 0.f;
#pragma unroll
  for (int j = 0; j < 8; j++) ps += x[j];
  float mean = wsum64(ps) * (1.0f / NG);
  float pq = 0.f;
#pragma unroll
  for (int j = 0; j < 8; j++) { float d = x[j] - mean; pq += d * d; }
  float rstd = rsqrtf(wsum64(pq) * (1.0f / NG) + 1e-5f);
  float4 g0 = *(const float4*)&lng[f], g1 = *(const float4*)&lng[f + 4];
  float4 b0 = *(const float4*)&lnb[f], b1 = *(const float4*)&lnb[f + 4];
  float gg[8] = {g0.x, g0.y, g0.z, g0.w, g1.x, g1.y, g1.z, g1.w};
  float bbv[8] = {b0.x, b0.y, b0.z, b0.w, b1.x, b1.y, b1.z, b1.w};
  bf16x8 ho;
#pragma unroll
  for (int j = 0; j < 8; j++) ho[j] = (short)f2bf((x[j] - mean) * rstd * gg[j] + bbv[j]);
  *(bf16x8*)&Hb[(size_t)ltok * NG + f] = ho;
}

// ---------- bf16 MFMA GEMM: 3-deep pipeline, counted vmcnt, swizzled LDS ----------
// BM=BN=128, BK=32, 4 waves (2x2), 4x4 16x16x32 frags per wave
// Steady state: STAGE(kt+2) -> compute kt -> vmcnt(4) [kt+1's loads done] -> barrier.
// Never drains vmcnt to 0 in the main loop (T4).
// mode: 1 = bf16 out relu, 3 = bf16 out no act
__global__ __launch_bounds__(256) void gemm_bf16(
    const ushort_t* __restrict__ A, const ushort_t* __restrict__ W,
    const float* __restrict__ bias, ushort_t* __restrict__ C,
    int K, int Dout, int mode) {
  __shared__ ushort_t As[3][4096];
  __shared__ ushort_t Bs[3][4096];
  const int t = threadIdx.x;
  const int w = t >> 6;
  const int lane = t & 63;
  const int wr = w >> 1, wc = w & 1;
  const int bm = blockIdx.x * 128, bn = blockIdx.y * 128;

  const int srow = lane >> 2;
  const int scol = (((lane & 3) ^ ((lane >> 3) & 3)) * 8);   // pre-swizzled source chunk
  const ushort_t* Ag0 = A + (size_t)(bm + w * 16 + srow) * K + scol;
  const ushort_t* Ag1 = A + (size_t)(bm + 64 + w * 16 + srow) * K + scol;
  const ushort_t* Wg0 = W + (size_t)(bn + w * 16 + srow) * K + scol;
  const ushort_t* Wg1 = W + (size_t)(bn + 64 + w * 16 + srow) * K + scol;
  const int l0 = w * 512;          // ushort offset, issue 0 (rows w*16..+16)
  const int l1 = 2048 + w * 512;   // issue 1 (rows 64+w*16..+16)

  const int lr = lane & 15;
  const int lq = lane >> 4;
  const int rchunk = (lq ^ ((lr >> 1) & 3)) * 8;   // swizzled read chunk

  f32x4 acc[4][4];
#pragma unroll
  for (int m = 0; m < 4; m++)
#pragma unroll
    for (int n = 0; n < 4; n++) acc[m][n] = (f32x4)0.f;

  const int nk = K >> 5;

#define STAGE(buf, kt)                                   \
  do {                                                   \
    const int kk_ = (kt) << 5;                           \
    gload_lds16(Ag0 + kk_, &As[(buf)][l0]);              \
    gload_lds16(Ag1 + kk_, &As[(buf)][l1]);              \
    gload_lds16(Wg0 + kk_, &Bs[(buf)][l0]);              \
    gload_lds16(Wg1 + kk_, &Bs[(buf)][l1]);              \
  } while (0)

  // prologue: stage tiles 0 and 1; wait tile 0 only (4 newest may stay in flight)
  STAGE(0, 0);
  if (nk > 1) {
    STAGE(1, 1);
    asm volatile("s_waitcnt vmcnt(4)" ::: "memory");
  } else {
    asm volatile("s_waitcnt vmcnt(0)" ::: "memory");
  }
  __builtin_amdgcn_sched_barrier(0);
  __builtin_amdgcn_s_barrier();
  __builtin_amdgcn_sched_barrier(0);

  int c0 = 0;
  for (int kt = 0; kt < nk; kt++) {
    const int c2 = (c0 >= 1) ? c0 - 1 : c0 + 2;   // (c0+2)%3
    if (kt + 2 < nk) STAGE(c2, kt + 2);           // prefetch distance 2
    bf16x8 a[4], b[4];
#pragma unroll
    for (int m = 0; m < 4; m++)
      a[m] = *(const bf16x8*)&As[c0][(wr * 64 + m * 16 + lr) * 32 + rchunk];
#pragma unroll
    for (int n = 0; n < 4; n++)
      b[n] = *(const bf16x8*)&Bs[c0][(wc * 64 + n * 16 + lr) * 32 + rchunk];
    __builtin_amdgcn_s_setprio(1);
#pragma unroll
    for (int m = 0; m < 4; m++)
#pragma unroll
      for (int n = 0; n < 4; n++)
        acc[m][n] = __builtin_amdgcn_mfma_f32_16x16x32_bf16(a[m], b[n], acc[m][n], 0, 0, 0);
    __builtin_amdgcn_s_setprio(0);
    // end-of-iter: ensure NEXT buffer's loads landed (counted — never 0 mid-loop)
    if (kt + 2 < nk) {
      asm volatile("s_waitcnt vmcnt(4)" ::: "memory");
    } else if (kt + 1 < nk) {
      asm volatile("s_waitcnt vmcnt(0)" ::: "memory");
    }
    __builtin_amdgcn_sched_barrier(0);
    __builtin_amdgcn_s_barrier();
    __builtin_amdgcn_sched_barrier(0);
    c0 = (c0 >= 2) ? 0 : c0 + 1;
  }
#undef STAGE

  // epilogue: C/D layout col = lane&15, row = (lane>>4)*4 + r
#pragma unroll
  for (int n = 0; n < 4; n++) {
    const int col = bn + wc * 64 + n * 16 + lr;
    const float bv = bias[col];
#pragma unroll
    for (int m = 0; m < 4; m++) {
      f32x4 v = acc[m][n];
#pragma unroll
      for (int r = 0; r < 4; r++) {
        int row = bm + wr * 64 + m * 16 + lq * 4 + r;
        float u = v[r] + bv;
        if (mode == 1) u = fmaxf(u, 0.f);
        C[(size_t)row * Dout + col] = f2bf(u);
      }
    }
  }
}

// ---------- GRU gates + post-LN, gi via PS gather (wave per token) ----------
__global__ __launch_bounds__(256) void gate_ln_kernel(
    const ushort_t* __restrict__ Gh, const ushort_t* __restrict__ Hb,
    const float* __restrict__ tcd, const float* __restrict__ PS,
    const float* __restrict__ b_ih, const float* __restrict__ lng,
    const float* __restrict__ lnb, ushort_t* __restrict__ X0) {
  const int t = threadIdx.x;
  const int lane = t & 63, wv = t >> 6;
  const int ltok = blockIdx.x * 4 + wv;
  const int f = lane * 8;
  int c[NE];
#pragma unroll
  for (int e = 0; e < NE; e++) {
    int ci = (int)tcd[(size_t)ltok * 8 + e];   // exact integer-valued fp32
    c[e] = ci > NOH ? NOH : ci;
  }
  float4 r0 = *(const float4*)&b_ih[f],          r1 = *(const float4*)&b_ih[f + 4];
  float4 z0 = *(const float4*)&b_ih[NG + f],     z1 = *(const float4*)&b_ih[NG + f + 4];
  float4 n0 = *(const float4*)&b_ih[2 * NG + f], n1 = *(const float4*)&b_ih[2 * NG + f + 4];
#pragma unroll
  for (int e = 0; e < NE; e++) {
    const float* pe = PS + ((size_t)(e * 21 + c[e])) * 1536;
    r0 += *(const float4*)&pe[f];          r1 += *(const float4*)&pe[f + 4];
    z0 += *(const float4*)&pe[NG + f];     z1 += *(const float4*)&pe[NG + f + 4];
    n0 += *(const float4*)&pe[2 * NG + f]; n1 += *(const float4*)&pe[2 * NG + f + 4];
  }
  float gir[8] = {r0.x, r0.y, r0.z, r0.w, r1.x, r1.y, r1.z, r1.w};
  float giz[8] = {z0.x, z0.y, z0.z, z0.w, z1.x, z1.y, z1.z, z1.w};
  float gin[8] = {n0.x, n0.y, n0.z, n0.w, n1.x, n1.y, n1.z, n1.w};

  const ushort_t* gh = Gh + (size_t)ltok * 1536;
  bf16x8 vr = *(const bf16x8*)&gh[f];
  bf16x8 vz = *(const bf16x8*)&gh[NG + f];
  bf16x8 vn = *(const bf16x8*)&gh[2 * NG + f];
  bf16x8 vh = *(const bf16x8*)&Hb[(size_t)ltok * NG + f];
  float cv[8];
  float ps = 0.f;
#pragma unroll
  for (int j = 0; j < 8; j++) {
    float rg = 1.f / (1.f + expf(-(gir[j] + bf2f((ushort_t)vr[j]))));
    float zg = 1.f / (1.f + expf(-(giz[j] + bf2f((ushort_t)vz[j]))));
    float ng = tanhf(gin[j] + rg * bf2f((ushort_t)vn[j]));
    cv[j] = (1.f - zg) * ng + zg * bf2f((ushort_t)vh[j]);
    ps += cv[j];
  }
  float mean = wsum64(ps) * (1.0f / NG);
  float pq = 0.f;
#pragma unroll
  for (int j = 0; j < 8; j++) { float d = cv[j] - mean; pq += d * d; }
  float rstd = rsqrtf(wsum64(pq) * (1.0f / NG) + 1e-5f);
  float4 g0 = *(const float4*)&lng[f], g1 = *(const float4*)&lng[f + 4];
  float4 b0 = *(const float4*)&lnb[f], b1 = *(const float4*)&lnb[f + 4];
  float gg[8] = {g0.x, g0.y, g0.z, g0.w, g1.x, g1.y, g1.z, g1.w};
  float bbv[8] = {b0.x, b0.y, b0.z, b0.w, b1.x, b1.y, b1.z, b1.w};
  bf16x8 xo;
#pragma unroll
  for (int j = 0; j < 8; j++) xo[j] = (short)f2bf((cv[j] - mean) * rstd * gg[j] + bbv[j]);
  *(bf16x8*)&X0[(size_t)ltok * NG + f] = xo;
}

// ---------- final LN + score (wave per token) ----------
__global__ __launch_bounds__(256) void ln_score_kernel(
    const ushort_t* __restrict__ X, const float* __restrict__ lng,
    const float* __restrict__ lnb, const float* __restrict__ Wsc,
    const float* __restrict__ bsc, float* __restrict__ scores) {
  const int t = threadIdx.x;
  const int lane = t & 63, wv = t >> 6;
  const int ltok = blockIdx.x * 4 + wv;
  const int f = lane * 8;
  bf16x8 xx = *(const bf16x8*)&X[(size_t)ltok * ND + f];
  float x[8];
  float ps = 0.f;
#pragma unroll
  for (int j = 0; j < 8; j++) { x[j] = bf2f((ushort_t)xx[j]); ps += x[j]; }
  float mean = wsum64(ps) * (1.0f / ND);
  float pq = 0.f;
#pragma unroll
  for (int j = 0; j < 8; j++) { float d = x[j] - mean; pq += d * d; }
  float rstd = rsqrtf(wsum64(pq) * (1.0f / ND) + 1e-5f);
  float4 g0 = *(const float4*)&lng[f], g1 = *(const float4*)&lng[f + 4];
  float4 b0 = *(const float4*)&lnb[f], b1 = *(const float4*)&lnb[f + 4];
  float4 w0 = *(const float4*)&Wsc[f], w1 = *(const float4*)&Wsc[f + 4];
  float gg[8] = {g0.x, g0.y, g0.z, g0.w, g1.x, g1.y, g1.z, g1.w};
  float bbv[8] = {b0.x, b0.y, b0.z, b0.w, b1.x, b1.y, b1.z, b1.w};
  float ww[8] = {w0.x, w0.y, w0.z, w0.w, w1.x, w1.y, w1.z, w1.w};
  float d = 0.f;
#pragma unroll
  for (int j = 0; j < 8; j++) d += ((x[j] - mean) * rstd * gg[j] + bbv[j]) * ww[j];
  float dot = wsum64(d);
  if (lane == 0) scores[ltok] = dot + bsc[0];
}

// ---------- fused softmax + LDS-spectrum scatter (one block per batch) ----------
__global__ __launch_bounds__(256) void softmax_scatter_kernel(
    const float* __restrict__ scores, const int* __restrict__ pidx,
    const float* __restrict__ pint, float* __restrict__ spect,
    float* __restrict__ probs) {
  const int b = blockIdx.x;
  const int t = threadIdx.x;
  __shared__ float s_red[4];
  __shared__ float s_spec[NBINS];
  const float* sc = scores + (size_t)b * NS;
  float v[4];
  float mx = -1e30f;
#pragma unroll
  for (int i = 0; i < 4; i++) { v[i] = sc[t + i * 256]; mx = fmaxf(mx, v[i]); }
#pragma unroll
  for (int off = 32; off > 0; off >>= 1) mx = fmaxf(mx, __shfl_down(mx, off));
  if ((t & 63) == 0) s_red[t >> 6] = mx;
  __syncthreads();
  mx = fmaxf(fmaxf(s_red[0], s_red[1]), fmaxf(s_red[2], s_red[3]));
  float e[4], sum = 0.f;
#pragma unroll
  for (int i = 0; i < 4; i++) { e[i] = expf(v[i] - mx); sum += e[i]; }
#pragma unroll
  for (int off = 32; off > 0; off >>= 1) sum += __shfl_down(sum, off);
  __syncthreads();
  if ((t & 63) == 0) s_red[t >> 6] = sum;
  __syncthreads();
  sum = s_red[0] + s_red[1] + s_red[2] + s_red[3];
  float inv = 1.f / sum;
  s_spec[t] = 0.f; s_spec[t + 256] = 0.f;
  float p[4];
#pragma unroll
  for (int i = 0; i < 4; i++) {
    p[i] = e[i] * inv;
    probs[(size_t)b * NS + t + i * 256] = p[i];
  }
  __syncthreads();
#pragma unroll
  for (int i = 0; i < 4; i++) {
    const int s = t + i * 256;
    const int* idx = pidx + ((size_t)b * NS + s) * NM;
    const float* wt = pint + ((size_t)b * NS + s) * NM;
#pragma unroll
    for (int m = 0; m < NM; m++)
      atomicAdd(&s_spec[idx[m]], wt[m] * p[i]);
  }
  __syncthreads();
  spect[(size_t)b * NBINS + t] = s_spec[t];
  spect[(size_t)b * NBINS + t + 256] = s_spec[t + 256];
}

extern "C" void kernel_launch(void* const* d_in, const int* in_sizes, int n_in,
                              void* d_out, int out_size, void* d_ws, size_t ws_size,
                              hipStream_t stream) {
  const float* vert = (const float*)d_in[0];
  const float* mask = (const float*)d_in[1];
  const float* eloh = (const float*)d_in[2];
  const int* subs = (const int*)d_in[3];
  const int* pidx = (const int*)d_in[4];
  const float* pint = (const float*)d_in[5];
  const float* ln_sub_g = (const float*)d_in[6];
  const float* ln_sub_b = (const float*)d_in[7];
  const float* W_ih = (const float*)d_in[8];
  const float* W_hh = (const float*)d_in[9];
  const float* b_ih = (const float*)d_in[10];
  const float* b_hh = (const float*)d_in[11];
  const float* ln_post_g = (const float*)d_in[12];
  const float* ln_post_b = (const float*)d_in[13];
  const float* W1 = (const float*)d_in[14];
  const float* b1 = (const float*)d_in[15];
  const float* W2a = (const float*)d_in[16];
  const float* b2a = (const float*)d_in[17];
  const float* W2b = (const float*)d_in[18];
  const float* b2b = (const float*)d_in[19];
  const float* ln_pre_g = (const float*)d_in[20];
  const float* ln_pre_b = (const float*)d_in[21];
  const float* W_s = (const float*)d_in[22];
  const float* b_s = (const float*)d_in[23];

  float* out = (float*)d_out;            // [0,8192) spect, [8192,24576) probs
  float* probs = out + NB * NBINS;

  // ---- fixed region ----
  char* ws = (char*)d_ws;
  float* scores = (float*)ws;                       // 64 KB
  ushort_t* Whh_bf = (ushort_t*)(ws + 65536);       // 1536*512*2 = 1572864
  ushort_t* W1_bf  = (ushort_t*)(ws + 1638400);     // 512*512*2 = 524288
  ushort_t* W2a_bf = (ushort_t*)(ws + 2162688);
  ushort_t* W2b_bf = (ushort_t*)(ws + 2686976);
  ushort_t* VmT    = (ushort_t*)(ws + 3211264);     // 16*512*32*2 = 524288
  ushort_t* S_bf   = (ushort_t*)(ws + 3735552);     // 16384*32*2 = 1048576
  float*    tcd    = (float*)(ws + 4784128);        // 16384*8*4 = 524288
  float*    PS     = (float*)(ws + 5308416);        // 5*21*1536*4 = 645120
  const size_t fixed = 5953536;

  // ---- chunked region; per-token bytes: SWV 2048 | Hb 1024 | Gh 3072 | X0 1024 = 7168
  const size_t per_tok = 7168;
  int T = NTOK;
  while (T > 1024 && fixed + (size_t)T * per_tok > ws_size) T >>= 1;
  const int nchunks = NTOK / T;

  char* cb = ws + fixed;
  float*    SWV = (float*)cb;                             cb += (size_t)T * 2048;
  ushort_t* Hb  = (ushort_t*)cb;                          cb += (size_t)T * 1024;
  ushort_t* Gh  = (ushort_t*)cb;                          cb += (size_t)T * 3072;
  ushort_t* X0  = (ushort_t*)cb;
  ushort_t* X1  = Gh;                  // Gh dead after gate_ln
  ushort_t* X2  = Gh + (size_t)T * 512;
  ushort_t* X3  = X0;                  // X0 dead after W1 GEMM

  // fused setup: invcnt + PS prefix table + 4 weight cvts + VmT prep + S_bf cvt
  const int setup_items = NTOK + NE * 1536 + 1536 * NG + ND * NG + 2 * ND * ND
                        + NB * NG * NA + NTOK * NA;
  setup_kernel<<<(setup_items + 255) / 256, 256, 0, stream>>>(
      vert, mask, eloh, subs, W_ih, W_hh, W1, W2a, W2b,
      tcd, PS, Whh_bf, W1_bf, W2a_bf, W2b_bf, VmT, S_bf);

  for (int c = 0; c < nchunks; c++) {
    const int tok0 = c * T;

    dim3 gp(T / 128, NG / 128);
    pool_gemm<<<gp, 256, 0, stream>>>(S_bf, VmT, tcd, SWV, tok0);
    finish_kernel<<<T / 4, 256, 0, stream>>>(SWV, ln_sub_g, ln_sub_b, Hb);

    dim3 g1(T / 128, 1536 / 128);
    gemm_bf16<<<g1, 256, 0, stream>>>(Hb, Whh_bf, b_hh, Gh, NG, 1536, 3);

    gate_ln_kernel<<<T / 4, 256, 0, stream>>>(Gh, Hb, tcd + (size_t)tok0 * 8, PS,
                                              b_ih, ln_post_g, ln_post_b, X0);

    dim3 g2(T / 128, ND / 128);
    gemm_bf16<<<g2, 256, 0, stream>>>(X0, W1_bf, b1, X1, NG, ND, 1);
    gemm_bf16<<<g2, 256, 0, stream>>>(X1, W2a_bf, b2a, X2, ND, ND, 1);
    gemm_bf16<<<g2, 256, 0, stream>>>(X2, W2b_bf, b2b, X3, ND, ND, 1);

    ln_score_kernel<<<T / 4, 256, 0, stream>>>(X3, ln_pre_g, ln_pre_b, W_s, b_s,
                                               scores + tok0);
  }

  softmax_scatter_kernel<<<NB, 256, 0, stream>>>(scores, pidx, pint, out, probs);
}

// Round 9
// 267.416 us; speedup vs baseline: 3.9177x; 1.0069x over previous
//
#include <hip/hip_runtime.h>

#define NB 16
#define NA 32
#define NG 512
#define NS 1024
#define NM 8
#define NE 5
#define NOH 20
#define NFE 100
#define ND 512
#define NBINS 512
#define NTOK (NB * NS)

typedef unsigned short ushort_t;
typedef __attribute__((ext_vector_type(8))) short bf16x8;
typedef __attribute__((ext_vector_type(4))) float f32x4;

__device__ __forceinline__ ushort_t f2bf(float x) {
  union { float f; unsigned u; } v; v.f = x;
  unsigned r = v.u + 0x7FFF + ((v.u >> 16) & 1);   // RNE
  return (ushort_t)(r >> 16);
}
__device__ __forceinline__ float bf2f(ushort_t b) {
  union { unsigned u; float f; } v; v.u = ((unsigned)b) << 16;
  return v.f;
}

__device__ __forceinline__ void gload_lds16(const void* g, void* l) {
  __builtin_amdgcn_global_load_lds(
      (const __attribute__((address_space(1))) void*)g,
      (__attribute__((address_space(3))) void*)l, 16, 0, 0);
}

// wave-wide (64 lanes) butterfly sum; all lanes get result
__device__ __forceinline__ float wsum64(float v) {
#pragma unroll
  for (int off = 32; off > 0; off >>= 1) v += __shfl_xor(v, off);
  return v;
}

// ---------- fused setup: invcnt | PS prefix table | weight cvt | VmT | S_bf ----------
__global__ __launch_bounds__(256) void setup_kernel(
    const float* __restrict__ vert, const float* __restrict__ mask,
    const float* __restrict__ eloh, const int* __restrict__ subs,
    const float* __restrict__ Wih, const float* __restrict__ Whh,
    const float* __restrict__ W1, const float* __restrict__ W2a,
    const float* __restrict__ W2b,
    float* __restrict__ tcd, float* __restrict__ PS,
    ushort_t* __restrict__ o_hh, ushort_t* __restrict__ o1,
    ushort_t* __restrict__ o2a, ushort_t* __restrict__ o2b,
    ushort_t* __restrict__ VmT, ushort_t* __restrict__ S_bf) {
  int i = blockIdx.x * 256 + threadIdx.x;
  if (i < NTOK) {   // per-token subset-size inverse + element counts (fp32 exact)
    int b = i >> 10;
    const int* srow = subs + (size_t)i * NA;
    float cnt[NE] = {0.f, 0.f, 0.f, 0.f, 0.f};
    float z = 0.f;
    for (int a = 0; a < NA; a++) {
      float sb = (float)srow[a];
      z += sb * mask[b * NA + a];
      const float* eo = eloh + (size_t)(b * NA + a) * NE;
#pragma unroll
      for (int e = 0; e < NE; e++) cnt[e] += eo[e] * sb;
    }
    float* o = tcd + (size_t)i * 8;
#pragma unroll
    for (int e = 0; e < NE; e++) o[e] = cnt[e];
    o[5] = 1.0f / (z + 1e-4f);
    return;
  }
  i -= NTOK;
  if (i < NE * 1536) {   // PS[e][c][g] = sum_{o<c} W_ih[g][e*20+o], fp32 exact
    int e = i / 1536, g = i % 1536;
    float s = 0.f;
    float* base = PS + ((size_t)e * 21) * 1536 + g;
    base[0] = 0.f;
    for (int c = 1; c <= NOH; c++) {
      s += Wih[(size_t)g * NFE + e * NOH + (c - 1)];
      base[(size_t)c * 1536] = s;
    }
    return;
  }
  i -= NE * 1536;
  if (i < 1536 * NG) { o_hh[i] = f2bf(Whh[i]); return; }
  i -= 1536 * NG;
  if (i < ND * NG) { o1[i] = f2bf(W1[i]); return; }
  i -= ND * NG;
  if (i < ND * ND) { o2a[i] = f2bf(W2a[i]); return; }
  i -= ND * ND;
  if (i < ND * ND) { o2b[i] = f2bf(W2b[i]); return; }
  i -= ND * ND;
  const int nV = NB * NG * NA;
  if (i < nV) {   // VmT[b][f][a] = bf16(vert*mask^2)
    int b = i / (NG * NA); int rem = i % (NG * NA);
    int f = rem >> 5, a = rem & 31;
    float mk = mask[b * NA + a];
    VmT[i] = f2bf(vert[(size_t)b * NA * NG + a * NG + f] * mk * mk);
    return;
  }
  i -= nV;
  if (i < NTOK * NA) S_bf[i] = f2bf((float)subs[i]);   // 0/1 exact
}

// ---------- pool GEMM: SWV[ltok][f] = (subs @ VmT^T) * inv  (K=32, one MFMA step) ----------
__global__ __launch_bounds__(256) void pool_gemm(
    const ushort_t* __restrict__ S_bf, const ushort_t* __restrict__ VmT,
    const float* __restrict__ tcd, float* __restrict__ SWV, int tok0) {
  __shared__ ushort_t As[128 * 32];
  __shared__ ushort_t Bs[128 * 32];
  const int t = threadIdx.x;
  const int w = t >> 6, lane = t & 63;
  const int wr = w >> 1, wc = w & 1;
  const int bm = blockIdx.x * 128;   // chunk-local token base
  const int bn = blockIdx.y * 128;   // f base
  const int b = (tok0 + bm) >> 10;   // 128 | 1024 so tile is single-batch
  const int srow = lane >> 2;
  const int scol = (((lane & 3) ^ ((lane >> 3) & 3)) * 8);   // pre-swizzled source chunk
  const ushort_t* Bbase = VmT + (size_t)b * NG * NA;
  gload_lds16(S_bf + (size_t)(tok0 + bm + w * 16 + srow) * 32 + scol, &As[w * 512]);
  gload_lds16(S_bf + (size_t)(tok0 + bm + 64 + w * 16 + srow) * 32 + scol, &As[2048 + w * 512]);
  gload_lds16(Bbase + (size_t)(bn + w * 16 + srow) * 32 + scol, &Bs[w * 512]);
  gload_lds16(Bbase + (size_t)(bn + 64 + w * 16 + srow) * 32 + scol, &Bs[2048 + w * 512]);
  __syncthreads();

  const int lr = lane & 15, lq = lane >> 4;
  const int rchunk = (lq ^ ((lr >> 1) & 3)) * 8;   // swizzled read chunk
  f32x4 acc[4][4];
#pragma unroll
  for (int m = 0; m < 4; m++)
#pragma unroll
    for (int n = 0; n < 4; n++) acc[m][n] = (f32x4)0.f;
  bf16x8 a[4], bb[4];
#pragma unroll
  for (int m = 0; m < 4; m++)
    a[m] = *(const bf16x8*)&As[(wr * 64 + m * 16 + lr) * 32 + rchunk];
#pragma unroll
  for (int n = 0; n < 4; n++)
    bb[n] = *(const bf16x8*)&Bs[(wc * 64 + n * 16 + lr) * 32 + rchunk];
#pragma unroll
  for (int m = 0; m < 4; m++)
#pragma unroll
    for (int n = 0; n < 4; n++)
      acc[m][n] = __builtin_amdgcn_mfma_f32_16x16x32_bf16(a[m], bb[n], acc[m][n], 0, 0, 0);

#pragma unroll
  for (int n = 0; n < 4; n++) {
    const int col = bn + wc * 64 + n * 16 + lr;
#pragma unroll
    for (int m = 0; m < 4; m++) {
      f32x4 v = acc[m][n];
#pragma unroll
      for (int r = 0; r < 4; r++) {
        int row = bm + wr * 64 + m * 16 + lq * 4 + r;
        float inv = tcd[(size_t)(tok0 + row) * 8 + 5];
        SWV[(size_t)row * NG + col] = v[r] * inv;
      }
    }
  }
}

// ---------- finish: LN(swv_mean) -> Hb bf16 (wave per token, 4 tokens/block) ----------
__global__ __launch_bounds__(256) void finish_kernel(
    const float* __restrict__ SWV, const float* __restrict__ lng,
    const float* __restrict__ lnb, ushort_t* __restrict__ Hb) {
  const int t = threadIdx.x;
  const int lane = t & 63, wv = t >> 6;
  const int ltok = blockIdx.x * 4 + wv;
  const int f = lane * 8;
  const float* row = SWV + (size_t)ltok * NG + f;
  float4 v0 = *(const float4*)row;
  float4 v1 = *(const float4*)(row + 4);
  float x[8] = {v0.x, v0.y, v0.z, v0.w, v1.x, v1.y, v1.z, v1.w};
  float ps = 0.f;
#pragma unroll
  for (int j = 0; j < 8; j++) ps += x[j];
  float mean = wsum64(ps) * (1.0f / NG);
  float pq = 0.f;
#pragma unroll
  for (int j = 0; j < 8; j++) { float d = x[j] - mean; pq += d * d; }
  float rstd = rsqrtf(wsum64(pq) * (1.0f / NG) + 1e-5f);
  float4 g0 = *(const float4*)&lng[f], g1 = *(const float4*)&lng[f + 4];
  float4 b0 = *(const float4*)&lnb[f], b1 = *(const float4*)&lnb[f + 4];
  float gg[8] = {g0.x, g0.y, g0.z, g0.w, g1.x, g1.y, g1.z, g1.w};
  float bbv[8] = {b0.x, b0.y, b0.z, b0.w, b1.x, b1.y, b1.z, b1.w};
  bf16x8 ho;
#pragma unroll
  for (int j = 0; j < 8; j++) ho[j] = (short)f2bf((x[j] - mean) * rstd * gg[j] + bbv[j]);
  *(bf16x8*)&Hb[(size_t)ltok * NG + f] = ho;
}

// ---------- bf16 MFMA GEMM, 2-phase double-buffer (compiler-scheduled) ----------
// BM=BN=128, BK=32, 4 waves (2x2), 4x4 16x16x32 frags per wave.
// Epilogue: pack bias+act+bf16 into per-wave 8KB LDS quadrant (XOR-swizzled),
// then coalesced dwordx4 stores (8 per lane; 128B contiguous per 8 lanes).
// mode: 1 = bf16 out relu, 3 = bf16 out no act
__global__ __launch_bounds__(256) void gemm_bf16(
    const ushort_t* __restrict__ A, const ushort_t* __restrict__ W,
    const float* __restrict__ bias, ushort_t* __restrict__ C,
    int K, int Dout, int mode) {
  __shared__ ushort_t As[2][4096];
  __shared__ ushort_t Bs[2][4096];
  const int t = threadIdx.x;
  const int w = t >> 6;
  const int lane = t & 63;
  const int wr = w >> 1, wc = w & 1;
  const int bm = blockIdx.x * 128, bn = blockIdx.y * 128;

  const int srow = lane >> 2;
  const int scol = (((lane & 3) ^ ((lane >> 3) & 3)) * 8);   // pre-swizzled source chunk
  const ushort_t* Ag0 = A + (size_t)(bm + w * 16 + srow) * K + scol;
  const ushort_t* Ag1 = A + (size_t)(bm + 64 + w * 16 + srow) * K + scol;
  const ushort_t* Wg0 = W + (size_t)(bn + w * 16 + srow) * K + scol;
  const ushort_t* Wg1 = W + (size_t)(bn + 64 + w * 16 + srow) * K + scol;
  const int l0 = w * 512;          // ushort offset, issue 0 (rows w*16..+16)
  const int l1 = 2048 + w * 512;   // issue 1 (rows 64+w*16..+16)

  const int lr = lane & 15;
  const int lq = lane >> 4;
  const int rchunk = (lq ^ ((lr >> 1) & 3)) * 8;   // swizzled read chunk

  f32x4 acc[4][4];
#pragma unroll
  for (int m = 0; m < 4; m++)
#pragma unroll
    for (int n = 0; n < 4; n++) acc[m][n] = (f32x4)0.f;

  // prologue: stage tile 0 into buf 0
  gload_lds16(Ag0, &As[0][l0]);
  gload_lds16(Ag1, &As[0][l1]);
  gload_lds16(Wg0, &Bs[0][l0]);
  gload_lds16(Wg1, &Bs[0][l1]);
  __syncthreads();

  const int nk = K >> 5;
  int cur = 0;
  for (int kt = 0; kt < nk; kt++) {
    if (kt + 1 < nk) {            // prefetch next tile into other buffer
      const int k1 = (kt + 1) << 5;
      gload_lds16(Ag0 + k1, &As[cur ^ 1][l0]);
      gload_lds16(Ag1 + k1, &As[cur ^ 1][l1]);
      gload_lds16(Wg0 + k1, &Bs[cur ^ 1][l0]);
      gload_lds16(Wg1 + k1, &Bs[cur ^ 1][l1]);
    }
    bf16x8 a[4], b[4];
#pragma unroll
    for (int m = 0; m < 4; m++)
      a[m] = *(const bf16x8*)&As[cur][(wr * 64 + m * 16 + lr) * 32 + rchunk];
#pragma unroll
    for (int n = 0; n < 4; n++)
      b[n] = *(const bf16x8*)&Bs[cur][(wc * 64 + n * 16 + lr) * 32 + rchunk];
#pragma unroll
    for (int m = 0; m < 4; m++)
#pragma unroll
      for (int n = 0; n < 4; n++)
        acc[m][n] = __builtin_amdgcn_mfma_f32_16x16x32_bf16(a[m], b[n], acc[m][n], 0, 0, 0);
    __syncthreads();   // drains lgkm (buf reads) and vm (prefetch) before swap
    cur ^= 1;
  }

  // ---- epilogue: per-wave LDS re-stage -> coalesced stores ----
  // After the loop's final barrier every wave is done with As/Bs; each wave
  // only touches its own 8KB quadrant, so no further syncs needed.
  ushort_t* sc = (w < 2) ? &As[w][0] : &Bs[w - 2][0];   // 4096 ushorts = 64x64 tile
  // pack: acc[m][n][r] (+bias, act) -> sc[row*64 + (col ^ ((row&7)<<3))]
#pragma unroll
  for (int n = 0; n < 4; n++) {
    const float bv = bias[bn + wc * 64 + n * 16 + lr];
#pragma unroll
    for (int m = 0; m < 4; m++) {
      f32x4 v = acc[m][n];
#pragma unroll
      for (int r = 0; r < 4; r++) {
        const int row = m * 16 + lq * 4 + r;
        float u = v[r] + bv;
        if (mode == 1) u = fmaxf(u, 0.f);
        sc[row * 64 + ((n * 16 + lr) ^ ((row & 7) << 3))] = f2bf(u);
      }
    }
  }
  __builtin_amdgcn_s_waitcnt(0);   // lgkmcnt(0): ds_writes visible to own-wave reads
  // store: 8 passes; lane reads 8 ushorts of row p*8+(lane>>3), writes dwordx4
#pragma unroll
  for (int p = 0; p < 8; p++) {
    const int row = p * 8 + (lane >> 3);
    bf16x8 pk = *(const bf16x8*)&sc[row * 64 + (((lane & 7) * 8) ^ ((row & 7) << 3))];
    *(bf16x8*)&C[(size_t)(bm + wr * 64 + row) * Dout + bn + wc * 64 + (lane & 7) * 8] = pk;
  }
}

// ---------- GRU gates + post-LN, gi via PS gather (wave per token) ----------
__global__ __launch_bounds__(256) void gate_ln_kernel(
    const ushort_t* __restrict__ Gh, const ushort_t* __restrict__ Hb,
    const float* __restrict__ tcd, const float* __restrict__ PS,
    const float* __restrict__ b_ih, const float* __restrict__ lng,
    const float* __restrict__ lnb, ushort_t* __restrict__ X0) {
  const int t = threadIdx.x;
  const int lane = t & 63, wv = t >> 6;
  const int ltok = blockIdx.x * 4 + wv;
  const int f = lane * 8;
  int c[NE];
#pragma unroll
  for (int e = 0; e < NE; e++) {
    int ci = (int)tcd[(size_t)ltok * 8 + e];   // exact integer-valued fp32
    c[e] = ci > NOH ? NOH : ci;
  }
  float4 r0 = *(const float4*)&b_ih[f],          r1 = *(const float4*)&b_ih[f + 4];
  float4 z0 = *(const float4*)&b_ih[NG + f],     z1 = *(const float4*)&b_ih[NG + f + 4];
  float4 n0 = *(const float4*)&b_ih[2 * NG + f], n1 = *(const float4*)&b_ih[2 * NG + f + 4];
#pragma unroll
  for (int e = 0; e < NE; e++) {
    const float* pe = PS + ((size_t)(e * 21 + c[e])) * 1536;
    r0 += *(const float4*)&pe[f];          r1 += *(const float4*)&pe[f + 4];
    z0 += *(const float4*)&pe[NG + f];     z1 += *(const float4*)&pe[NG + f + 4];
    n0 += *(const float4*)&pe[2 * NG + f]; n1 += *(const float4*)&pe[2 * NG + f + 4];
  }
  float gir[8] = {r0.x, r0.y, r0.z, r0.w, r1.x, r1.y, r1.z, r1.w};
  float giz[8] = {z0.x, z0.y, z0.z, z0.w, z1.x, z1.y, z1.z, z1.w};
  float gin[8] = {n0.x, n0.y, n0.z, n0.w, n1.x, n1.y, n1.z, n1.w};

  const ushort_t* gh = Gh + (size_t)ltok * 1536;
  bf16x8 vr = *(const bf16x8*)&gh[f];
  bf16x8 vz = *(const bf16x8*)&gh[NG + f];
  bf16x8 vn = *(const bf16x8*)&gh[2 * NG + f];
  bf16x8 vh = *(const bf16x8*)&Hb[(size_t)ltok * NG + f];
  float cv[8];
  float ps = 0.f;
#pragma unroll
  for (int j = 0; j < 8; j++) {
    float rg = 1.f / (1.f + expf(-(gir[j] + bf2f((ushort_t)vr[j]))));
    float zg = 1.f / (1.f + expf(-(giz[j] + bf2f((ushort_t)vz[j]))));
    float ng = tanhf(gin[j] + rg * bf2f((ushort_t)vn[j]));
    cv[j] = (1.f - zg) * ng + zg * bf2f((ushort_t)vh[j]);
    ps += cv[j];
  }
  float mean = wsum64(ps) * (1.0f / NG);
  float pq = 0.f;
#pragma unroll
  for (int j = 0; j < 8; j++) { float d = cv[j] - mean; pq += d * d; }
  float rstd = rsqrtf(wsum64(pq) * (1.0f / NG) + 1e-5f);
  float4 g0 = *(const float4*)&lng[f], g1 = *(const float4*)&lng[f + 4];
  float4 b0 = *(const float4*)&lnb[f], b1 = *(const float4*)&lnb[f + 4];
  float gg[8] = {g0.x, g0.y, g0.z, g0.w, g1.x, g1.y, g1.z, g1.w};
  float bbv[8] = {b0.x, b0.y, b0.z, b0.w, b1.x, b1.y, b1.z, b1.w};
  bf16x8 xo;
#pragma unroll
  for (int j = 0; j < 8; j++) xo[j] = (short)f2bf((cv[j] - mean) * rstd * gg[j] + bbv[j]);
  *(bf16x8*)&X0[(size_t)ltok * NG + f] = xo;
}

// ---------- final LN + score (wave per token) ----------
__global__ __launch_bounds__(256) void ln_score_kernel(
    const ushort_t* __restrict__ X, const float* __restrict__ lng,
    const float* __restrict__ lnb, const float* __restrict__ Wsc,
    const float* __restrict__ bsc, float* __restrict__ scores) {
  const int t = threadIdx.x;
  const int lane = t & 63, wv = t >> 6;
  const int ltok = blockIdx.x * 4 + wv;
  const int f = lane * 8;
  bf16x8 xx = *(const bf16x8*)&X[(size_t)ltok * ND + f];
  float x[8];
  float ps = 0.f;
#pragma unroll
  for (int j = 0; j < 8; j++) { x[j] = bf2f((ushort_t)xx[j]); ps += x[j]; }
  float mean = wsum64(ps) * (1.0f / ND);
  float pq = 0.f;
#pragma unroll
  for (int j = 0; j < 8; j++) { float d = x[j] - mean; pq += d * d; }
  float rstd = rsqrtf(wsum64(pq) * (1.0f / ND) + 1e-5f);
  float4 g0 = *(const float4*)&lng[f], g1 = *(const float4*)&lng[f + 4];
  float4 b0 = *(const float4*)&lnb[f], b1 = *(const float4*)&lnb[f + 4];
  float4 w0 = *(const float4*)&Wsc[f], w1 = *(const float4*)&Wsc[f + 4];
  float gg[8] = {g0.x, g0.y, g0.z, g0.w, g1.x, g1.y, g1.z, g1.w};
  float bbv[8] = {b0.x, b0.y, b0.z, b0.w, b1.x, b1.y, b1.z, b1.w};
  float ww[8] = {w0.x, w0.y, w0.z, w0.w, w1.x, w1.y, w1.z, w1.w};
  float d = 0.f;
#pragma unroll
  for (int j = 0; j < 8; j++) d += ((x[j] - mean) * rstd * gg[j] + bbv[j]) * ww[j];
  float dot = wsum64(d);
  if (lane == 0) scores[ltok] = dot + bsc[0];
}

// ---------- fused softmax + LDS-spectrum scatter (one block per batch) ----------
__global__ __launch_bounds__(256) void softmax_scatter_kernel(
    const float* __restrict__ scores, const int* __restrict__ pidx,
    const float* __restrict__ pint, float* __restrict__ spect,
    float* __restrict__ probs) {
  const int b = blockIdx.x;
  const int t = threadIdx.x;
  __shared__ float s_red[4];
  __shared__ float s_spec[NBINS];
  const float* sc = scores + (size_t)b * NS;
  float v[4];
  float mx = -1e30f;
#pragma unroll
  for (int i = 0; i < 4; i++) { v[i] = sc[t + i * 256]; mx = fmaxf(mx, v[i]); }
#pragma unroll
  for (int off = 32; off > 0; off >>= 1) mx = fmaxf(mx, __shfl_down(mx, off));
  if ((t & 63) == 0) s_red[t >> 6] = mx;
  __syncthreads();
  mx = fmaxf(fmaxf(s_red[0], s_red[1]), fmaxf(s_red[2], s_red[3]));
  float e[4], sum = 0.f;
#pragma unroll
  for (int i = 0; i < 4; i++) { e[i] = expf(v[i] - mx); sum += e[i]; }
#pragma unroll
  for (int off = 32; off > 0; off >>= 1) sum += __shfl_down(sum, off);
  __syncthreads();
  if ((t & 63) == 0) s_red[t >> 6] = sum;
  __syncthreads();
  sum = s_red[0] + s_red[1] + s_red[2] + s_red[3];
  float inv = 1.f / sum;
  s_spec[t] = 0.f; s_spec[t + 256] = 0.f;
  float p[4];
#pragma unroll
  for (int i = 0; i < 4; i++) {
    p[i] = e[i] * inv;
    probs[(size_t)b * NS + t + i * 256] = p[i];
  }
  __syncthreads();
#pragma unroll
  for (int i = 0; i < 4; i++) {
    const int s = t + i * 256;
    const int* idx = pidx + ((size_t)b * NS + s) * NM;
    const float* wt = pint + ((size_t)b * NS + s) * NM;
#pragma unroll
    for (int m = 0; m < NM; m++)
      atomicAdd(&s_spec[idx[m]], wt[m] * p[i]);
  }
  __syncthreads();
  spect[(size_t)b * NBINS + t] = s_spec[t];
  spect[(size_t)b * NBINS + t + 256] = s_spec[t + 256];
}

extern "C" void kernel_launch(void* const* d_in, const int* in_sizes, int n_in,
                              void* d_out, int out_size, void* d_ws, size_t ws_size,
                              hipStream_t stream) {
  const float* vert = (const float*)d_in[0];
  const float* mask = (const float*)d_in[1];
  const float* eloh = (const float*)d_in[2];
  const int* subs = (const int*)d_in[3];
  const int* pidx = (const int*)d_in[4];
  const float* pint = (const float*)d_in[5];
  const float* ln_sub_g = (const float*)d_in[6];
  const float* ln_sub_b = (const float*)d_in[7];
  const float* W_ih = (const float*)d_in[8];
  const float* W_hh = (const float*)d_in[9];
  const float* b_ih = (const float*)d_in[10];
  const float* b_hh = (const float*)d_in[11];
  const float* ln_post_g = (const float*)d_in[12];
  const float* ln_post_b = (const float*)d_in[13];
  const float* W1 = (const float*)d_in[14];
  const float* b1 = (const float*)d_in[15];
  const float* W2a = (const float*)d_in[16];
  const float* b2a = (const float*)d_in[17];
  const float* W2b = (const float*)d_in[18];
  const float* b2b = (const float*)d_in[19];
  const float* ln_pre_g = (const float*)d_in[20];
  const float* ln_pre_b = (const float*)d_in[21];
  const float* W_s = (const float*)d_in[22];
  const float* b_s = (const float*)d_in[23];

  float* out = (float*)d_out;            // [0,8192) spect, [8192,24576) probs
  float* probs = out + NB * NBINS;

  // ---- fixed region ----
  char* ws = (char*)d_ws;
  float* scores = (float*)ws;                       // 64 KB
  ushort_t* Whh_bf = (ushort_t*)(ws + 65536);       // 1536*512*2 = 1572864
  ushort_t* W1_bf  = (ushort_t*)(ws + 1638400);     // 512*512*2 = 524288
  ushort_t* W2a_bf = (ushort_t*)(ws + 2162688);
  ushort_t* W2b_bf = (ushort_t*)(ws + 2686976);
  ushort_t* VmT    = (ushort_t*)(ws + 3211264);     // 16*512*32*2 = 524288
  ushort_t* S_bf   = (ushort_t*)(ws + 3735552);     // 16384*32*2 = 1048576
  float*    tcd    = (float*)(ws + 4784128);        // 16384*8*4 = 524288
  float*    PS     = (float*)(ws + 5308416);        // 5*21*1536*4 = 645120
  const size_t fixed = 5953536;

  // ---- chunked region; per-token bytes: SWV 2048 | Hb 1024 | Gh 3072 | X0 1024 = 7168
  const size_t per_tok = 7168;
  int T = NTOK;
  while (T > 1024 && fixed + (size_t)T * per_tok > ws_size) T >>= 1;
  const int nchunks = NTOK / T;

  char* cb = ws + fixed;
  float*    SWV = (float*)cb;                             cb += (size_t)T * 2048;
  ushort_t* Hb  = (ushort_t*)cb;                          cb += (size_t)T * 1024;
  ushort_t* Gh  = (ushort_t*)cb;                          cb += (size_t)T * 3072;
  ushort_t* X0  = (ushort_t*)cb;
  ushort_t* X1  = Gh;                  // Gh dead after gate_ln
  ushort_t* X2  = Gh + (size_t)T * 512;
  ushort_t* X3  = X0;                  // X0 dead after W1 GEMM

  // fused setup: invcnt + PS prefix table + 4 weight cvts + VmT prep + S_bf cvt
  const int setup_items = NTOK + NE * 1536 + 1536 * NG + ND * NG + 2 * ND * ND
                        + NB * NG * NA + NTOK * NA;
  setup_kernel<<<(setup_items + 255) / 256, 256, 0, stream>>>(
      vert, mask, eloh, subs, W_ih, W_hh, W1, W2a, W2b,
      tcd, PS, Whh_bf, W1_bf, W2a_bf, W2b_bf, VmT, S_bf);

  for (int c = 0; c < nchunks; c++) {
    const int tok0 = c * T;

    dim3 gp(T / 128, NG / 128);
    pool_gemm<<<gp, 256, 0, stream>>>(S_bf, VmT, tcd, SWV, tok0);
    finish_kernel<<<T / 4, 256, 0, stream>>>(SWV, ln_sub_g, ln_sub_b, Hb);

    dim3 g1(T / 128, 1536 / 128);
    gemm_bf16<<<g1, 256, 0, stream>>>(Hb, Whh_bf, b_hh, Gh, NG, 1536, 3);

    gate_ln_kernel<<<T / 4, 256, 0, stream>>>(Gh, Hb, tcd + (size_t)tok0 * 8, PS,
                                              b_ih, ln_post_g, ln_post_b, X0);

    dim3 g2(T / 128, ND / 128);
    gemm_bf16<<<g2, 256, 0, stream>>>(X0, W1_bf, b1, X1, NG, ND, 1);
    gemm_bf16<<<g2, 256, 0, stream>>>(X1, W2a_bf, b2a, X2, ND, ND, 1);
    gemm_bf16<<<g2, 256, 0, stream>>>(X2, W2b_bf, b2b, X3, ND, ND, 1);

    ln_score_kernel<<<T / 4, 256, 0, stream>>>(X3, ln_pre_g, ln_pre_b, W_s, b_s,
                                               scores + tok0);
  }

  softmax_scatter_kernel<<<NB, 256, 0, stream>>>(scores, pidx, pint, out, probs);
}

// Round 10
// 263.370 us; speedup vs baseline: 3.9779x; 1.0154x over previous
//
#include <hip/hip_runtime.h>

#define NB 16
#define NA 32
#define NG 512
#define NS 1024
#define NM 8
#define NE 5
#define NOH 20
#define NFE 100
#define ND 512
#define NBINS 512
#define NTOK (NB * NS)

typedef unsigned short ushort_t;
typedef __attribute__((ext_vector_type(8))) short bf16x8;
typedef __attribute__((ext_vector_type(4))) float f32x4;

__device__ __forceinline__ ushort_t f2bf(float x) {
  union { float f; unsigned u; } v; v.f = x;
  unsigned r = v.u + 0x7FFF + ((v.u >> 16) & 1);   // RNE
  return (ushort_t)(r >> 16);
}
__device__ __forceinline__ float bf2f(ushort_t b) {
  union { unsigned u; float f; } v; v.u = ((unsigned)b) << 16;
  return v.f;
}

__device__ __forceinline__ void gload_lds16(const void* g, void* l) {
  __builtin_amdgcn_global_load_lds(
      (const __attribute__((address_space(1))) void*)g,
      (__attribute__((address_space(3))) void*)l, 16, 0, 0);
}

// wave-wide (64 lanes) butterfly sum; all lanes get result
__device__ __forceinline__ float wsum64(float v) {
#pragma unroll
  for (int off = 32; off > 0; off >>= 1) v += __shfl_xor(v, off);
  return v;
}

// fast native sigmoid/tanh (v_exp_f32 + v_rcp_f32; err ~1e-6 << bf16 rounding)
__device__ __forceinline__ float fsig(float x) {
  return __builtin_amdgcn_rcpf(1.f + __expf(-x));   // x<-88: exp->inf, rcp->0 (correct)
}
__device__ __forceinline__ float ftanh(float x) {
  float t = fminf(fmaxf(x, -15.f), 15.f);           // keep exp finite; tanh sat by |x|>9
  return 1.f - 2.f * __builtin_amdgcn_rcpf(__expf(2.f * t) + 1.f);
}

// ---------- fused setup: invcnt | PS prefix table | weight cvt | VmT | S_bf ----------
__global__ __launch_bounds__(256) void setup_kernel(
    const float* __restrict__ vert, const float* __restrict__ mask,
    const float* __restrict__ eloh, const int* __restrict__ subs,
    const float* __restrict__ Wih, const float* __restrict__ Whh,
    const float* __restrict__ W1, const float* __restrict__ W2a,
    const float* __restrict__ W2b,
    float* __restrict__ tcd, float* __restrict__ PS,
    ushort_t* __restrict__ o_hh, ushort_t* __restrict__ o1,
    ushort_t* __restrict__ o2a, ushort_t* __restrict__ o2b,
    ushort_t* __restrict__ VmT, ushort_t* __restrict__ S_bf) {
  int i = blockIdx.x * 256 + threadIdx.x;
  if (i < NTOK) {   // per-token subset-size inverse + element counts (fp32 exact)
    int b = i >> 10;
    const int* srow = subs + (size_t)i * NA;
    float cnt[NE] = {0.f, 0.f, 0.f, 0.f, 0.f};
    float z = 0.f;
    for (int a = 0; a < NA; a++) {
      float sb = (float)srow[a];
      z += sb * mask[b * NA + a];
      const float* eo = eloh + (size_t)(b * NA + a) * NE;
#pragma unroll
      for (int e = 0; e < NE; e++) cnt[e] += eo[e] * sb;
    }
    float* o = tcd + (size_t)i * 8;
#pragma unroll
    for (int e = 0; e < NE; e++) o[e] = cnt[e];
    o[5] = 1.0f / (z + 1e-4f);
    return;
  }
  i -= NTOK;
  if (i < NE * 1536) {   // PS[e][c][g] = sum_{o<c} W_ih[g][e*20+o], fp32 exact
    int e = i / 1536, g = i % 1536;
    float s = 0.f;
    float* base = PS + ((size_t)e * 21) * 1536 + g;
    base[0] = 0.f;
    for (int c = 1; c <= NOH; c++) {
      s += Wih[(size_t)g * NFE + e * NOH + (c - 1)];
      base[(size_t)c * 1536] = s;
    }
    return;
  }
  i -= NE * 1536;
  if (i < 1536 * NG) { o_hh[i] = f2bf(Whh[i]); return; }
  i -= 1536 * NG;
  if (i < ND * NG) { o1[i] = f2bf(W1[i]); return; }
  i -= ND * NG;
  if (i < ND * ND) { o2a[i] = f2bf(W2a[i]); return; }
  i -= ND * ND;
  if (i < ND * ND) { o2b[i] = f2bf(W2b[i]); return; }
  i -= ND * ND;
  const int nV = NB * NG * NA;
  if (i < nV) {   // VmT[b][f][a] = bf16(vert*mask^2)
    int b = i / (NG * NA); int rem = i % (NG * NA);
    int f = rem >> 5, a = rem & 31;
    float mk = mask[b * NA + a];
    VmT[i] = f2bf(vert[(size_t)b * NA * NG + a * NG + f] * mk * mk);
    return;
  }
  i -= nV;
  if (i < NTOK * NA) S_bf[i] = f2bf((float)subs[i]);   // 0/1 exact
}

// ---------- pool GEMM: SWV[ltok][f] = (subs @ VmT^T) * inv  (K=32, one MFMA step) ----------
__global__ __launch_bounds__(256) void pool_gemm(
    const ushort_t* __restrict__ S_bf, const ushort_t* __restrict__ VmT,
    const float* __restrict__ tcd, float* __restrict__ SWV, int tok0) {
  __shared__ ushort_t As[128 * 32];
  __shared__ ushort_t Bs[128 * 32];
  const int t = threadIdx.x;
  const int w = t >> 6, lane = t & 63;
  const int wr = w >> 1, wc = w & 1;
  const int bm = blockIdx.x * 128;   // chunk-local token base
  const int bn = blockIdx.y * 128;   // f base
  const int b = (tok0 + bm) >> 10;   // 128 | 1024 so tile is single-batch
  const int srow = lane >> 2;
  const int scol = (((lane & 3) ^ ((lane >> 3) & 3)) * 8);   // pre-swizzled source chunk
  const ushort_t* Bbase = VmT + (size_t)b * NG * NA;
  gload_lds16(S_bf + (size_t)(tok0 + bm + w * 16 + srow) * 32 + scol, &As[w * 512]);
  gload_lds16(S_bf + (size_t)(tok0 + bm + 64 + w * 16 + srow) * 32 + scol, &As[2048 + w * 512]);
  gload_lds16(Bbase + (size_t)(bn + w * 16 + srow) * 32 + scol, &Bs[w * 512]);
  gload_lds16(Bbase + (size_t)(bn + 64 + w * 16 + srow) * 32 + scol, &Bs[2048 + w * 512]);
  __syncthreads();

  const int lr = lane & 15, lq = lane >> 4;
  const int rchunk = (lq ^ ((lr >> 1) & 3)) * 8;   // swizzled read chunk
  f32x4 acc[4][4];
#pragma unroll
  for (int m = 0; m < 4; m++)
#pragma unroll
    for (int n = 0; n < 4; n++) acc[m][n] = (f32x4)0.f;
  bf16x8 a[4], bb[4];
#pragma unroll
  for (int m = 0; m < 4; m++)
    a[m] = *(const bf16x8*)&As[(wr * 64 + m * 16 + lr) * 32 + rchunk];
#pragma unroll
  for (int n = 0; n < 4; n++)
    bb[n] = *(const bf16x8*)&Bs[(wc * 64 + n * 16 + lr) * 32 + rchunk];
#pragma unroll
  for (int m = 0; m < 4; m++)
#pragma unroll
    for (int n = 0; n < 4; n++)
      acc[m][n] = __builtin_amdgcn_mfma_f32_16x16x32_bf16(a[m], bb[n], acc[m][n], 0, 0, 0);

#pragma unroll
  for (int n = 0; n < 4; n++) {
    const int col = bn + wc * 64 + n * 16 + lr;
#pragma unroll
    for (int m = 0; m < 4; m++) {
      f32x4 v = acc[m][n];
#pragma unroll
      for (int r = 0; r < 4; r++) {
        int row = bm + wr * 64 + m * 16 + lq * 4 + r;
        float inv = tcd[(size_t)(tok0 + row) * 8 + 5];
        SWV[(size_t)row * NG + col] = v[r] * inv;
      }
    }
  }
}

// ---------- finish: LN(swv_mean) -> Hb bf16 (wave per token, 4 tokens/block) ----------
__global__ __launch_bounds__(256) void finish_kernel(
    const float* __restrict__ SWV, const float* __restrict__ lng,
    const float* __restrict__ lnb, ushort_t* __restrict__ Hb) {
  const int t = threadIdx.x;
  const int lane = t & 63, wv = t >> 6;
  const int ltok = blockIdx.x * 4 + wv;
  const int f = lane * 8;
  const float* row = SWV + (size_t)ltok * NG + f;
  float4 v0 = *(const float4*)row;
  float4 v1 = *(const float4*)(row + 4);
  float x[8] = {v0.x, v0.y, v0.z, v0.w, v1.x, v1.y, v1.z, v1.w};
  float ps = 0.f;
#pragma unroll
  for (int j = 0; j < 8; j++) ps += x[j];
  float mean = wsum64(ps) * (1.0f / NG);
  float pq = 0.f;
#pragma unroll
  for (int j = 0; j < 8; j++) { float d = x[j] - mean; pq += d * d; }
  float rstd = rsqrtf(wsum64(pq) * (1.0f / NG) + 1e-5f);
  float4 g0 = *(const float4*)&lng[f], g1 = *(const float4*)&lng[f + 4];
  float4 b0 = *(const float4*)&lnb[f], b1 = *(const float4*)&lnb[f + 4];
  float gg[8] = {g0.x, g0.y, g0.z, g0.w, g1.x, g1.y, g1.z, g1.w};
  float bbv[8] = {b0.x, b0.y, b0.z, b0.w, b1.x, b1.y, b1.z, b1.w};
  bf16x8 ho;
#pragma unroll
  for (int j = 0; j < 8; j++) ho[j] = (short)f2bf((x[j] - mean) * rstd * gg[j] + bbv[j]);
  *(bf16x8*)&Hb[(size_t)ltok * NG + f] = ho;
}

// ---------- bf16 MFMA GEMM, 2-phase double-buffer (compiler-scheduled) ----------
// BM=BN=128, BK=32, 4 waves (2x2), 4x4 16x16x32 frags per wave.
// Epilogue: pack bias+act+bf16 into per-wave 8KB LDS quadrant (XOR-swizzled),
// then coalesced dwordx4 stores (8 per lane; 128B contiguous per 8 lanes).
// mode: 1 = bf16 out relu, 3 = bf16 out no act
__global__ __launch_bounds__(256) void gemm_bf16(
    const ushort_t* __restrict__ A, const ushort_t* __restrict__ W,
    const float* __restrict__ bias, ushort_t* __restrict__ C,
    int K, int Dout, int mode) {
  __shared__ ushort_t As[2][4096];
  __shared__ ushort_t Bs[2][4096];
  const int t = threadIdx.x;
  const int w = t >> 6;
  const int lane = t & 63;
  const int wr = w >> 1, wc = w & 1;
  const int bm = blockIdx.x * 128, bn = blockIdx.y * 128;

  const int srow = lane >> 2;
  const int scol = (((lane & 3) ^ ((lane >> 3) & 3)) * 8);   // pre-swizzled source chunk
  const ushort_t* Ag0 = A + (size_t)(bm + w * 16 + srow) * K + scol;
  const ushort_t* Ag1 = A + (size_t)(bm + 64 + w * 16 + srow) * K + scol;
  const ushort_t* Wg0 = W + (size_t)(bn + w * 16 + srow) * K + scol;
  const ushort_t* Wg1 = W + (size_t)(bn + 64 + w * 16 + srow) * K + scol;
  const int l0 = w * 512;          // ushort offset, issue 0 (rows w*16..+16)
  const int l1 = 2048 + w * 512;   // issue 1 (rows 64+w*16..+16)

  const int lr = lane & 15;
  const int lq = lane >> 4;
  const int rchunk = (lq ^ ((lr >> 1) & 3)) * 8;   // swizzled read chunk

  f32x4 acc[4][4];
#pragma unroll
  for (int m = 0; m < 4; m++)
#pragma unroll
    for (int n = 0; n < 4; n++) acc[m][n] = (f32x4)0.f;

  // prologue: stage tile 0 into buf 0
  gload_lds16(Ag0, &As[0][l0]);
  gload_lds16(Ag1, &As[0][l1]);
  gload_lds16(Wg0, &Bs[0][l0]);
  gload_lds16(Wg1, &Bs[0][l1]);
  __syncthreads();

  const int nk = K >> 5;
  int cur = 0;
  for (int kt = 0; kt < nk; kt++) {
    if (kt + 1 < nk) {            // prefetch next tile into other buffer
      const int k1 = (kt + 1) << 5;
      gload_lds16(Ag0 + k1, &As[cur ^ 1][l0]);
      gload_lds16(Ag1 + k1, &As[cur ^ 1][l1]);
      gload_lds16(Wg0 + k1, &Bs[cur ^ 1][l0]);
      gload_lds16(Wg1 + k1, &Bs[cur ^ 1][l1]);
    }
    bf16x8 a[4], b[4];
#pragma unroll
    for (int m = 0; m < 4; m++)
      a[m] = *(const bf16x8*)&As[cur][(wr * 64 + m * 16 + lr) * 32 + rchunk];
#pragma unroll
    for (int n = 0; n < 4; n++)
      b[n] = *(const bf16x8*)&Bs[cur][(wc * 64 + n * 16 + lr) * 32 + rchunk];
#pragma unroll
    for (int m = 0; m < 4; m++)
#pragma unroll
      for (int n = 0; n < 4; n++)
        acc[m][n] = __builtin_amdgcn_mfma_f32_16x16x32_bf16(a[m], b[n], acc[m][n], 0, 0, 0);
    __syncthreads();   // drains lgkm (buf reads) and vm (prefetch) before swap
    cur ^= 1;
  }

  // ---- epilogue: per-wave LDS re-stage -> coalesced stores ----
  ushort_t* sc = (w < 2) ? &As[w][0] : &Bs[w - 2][0];   // 4096 ushorts = 64x64 tile
#pragma unroll
  for (int n = 0; n < 4; n++) {
    const float bv = bias[bn + wc * 64 + n * 16 + lr];
#pragma unroll
    for (int m = 0; m < 4; m++) {
      f32x4 v = acc[m][n];
#pragma unroll
      for (int r = 0; r < 4; r++) {
        const int row = m * 16 + lq * 4 + r;
        float u = v[r] + bv;
        if (mode == 1) u = fmaxf(u, 0.f);
        sc[row * 64 + ((n * 16 + lr) ^ ((row & 7) << 3))] = f2bf(u);
      }
    }
  }
  __builtin_amdgcn_s_waitcnt(0);   // lgkmcnt(0): ds_writes visible to own-wave reads
#pragma unroll
  for (int p = 0; p < 8; p++) {
    const int row = p * 8 + (lane >> 3);
    bf16x8 pk = *(const bf16x8*)&sc[row * 64 + (((lane & 7) * 8) ^ ((row & 7) << 3))];
    *(bf16x8*)&C[(size_t)(bm + wr * 64 + row) * Dout + bn + wc * 64 + (lane & 7) * 8] = pk;
  }
}

// ---------- GRU gates + post-LN, gi via PS gather (wave per token) ----------
__global__ __launch_bounds__(256) void gate_ln_kernel(
    const ushort_t* __restrict__ Gh, const ushort_t* __restrict__ Hb,
    const float* __restrict__ tcd, const float* __restrict__ PS,
    const float* __restrict__ b_ih, const float* __restrict__ lng,
    const float* __restrict__ lnb, ushort_t* __restrict__ X0) {
  const int t = threadIdx.x;
  const int lane = t & 63, wv = t >> 6;
  const int ltok = blockIdx.x * 4 + wv;
  const int f = lane * 8;
  int c[NE];
#pragma unroll
  for (int e = 0; e < NE; e++) {
    int ci = (int)tcd[(size_t)ltok * 8 + e];   // exact integer-valued fp32
    c[e] = ci > NOH ? NOH : ci;
  }
  float4 r0 = *(const float4*)&b_ih[f],          r1 = *(const float4*)&b_ih[f + 4];
  float4 z0 = *(const float4*)&b_ih[NG + f],     z1 = *(const float4*)&b_ih[NG + f + 4];
  float4 n0 = *(const float4*)&b_ih[2 * NG + f], n1 = *(const float4*)&b_ih[2 * NG + f + 4];
#pragma unroll
  for (int e = 0; e < NE; e++) {
    const float* pe = PS + ((size_t)(e * 21 + c[e])) * 1536;
    r0 += *(const float4*)&pe[f];          r1 += *(const float4*)&pe[f + 4];
    z0 += *(const float4*)&pe[NG + f];     z1 += *(const float4*)&pe[NG + f + 4];
    n0 += *(const float4*)&pe[2 * NG + f]; n1 += *(const float4*)&pe[2 * NG + f + 4];
  }
  float gir[8] = {r0.x, r0.y, r0.z, r0.w, r1.x, r1.y, r1.z, r1.w};
  float giz[8] = {z0.x, z0.y, z0.z, z0.w, z1.x, z1.y, z1.z, z1.w};
  float gin[8] = {n0.x, n0.y, n0.z, n0.w, n1.x, n1.y, n1.z, n1.w};

  const ushort_t* gh = Gh + (size_t)ltok * 1536;
  bf16x8 vr = *(const bf16x8*)&gh[f];
  bf16x8 vz = *(const bf16x8*)&gh[NG + f];
  bf16x8 vn = *(const bf16x8*)&gh[2 * NG + f];
  bf16x8 vh = *(const bf16x8*)&Hb[(size_t)ltok * NG + f];
  float cv[8];
  float ps = 0.f;
#pragma unroll
  for (int j = 0; j < 8; j++) {
    float rg = fsig(gir[j] + bf2f((ushort_t)vr[j]));
    float zg = fsig(giz[j] + bf2f((ushort_t)vz[j]));
    float ng = ftanh(gin[j] + rg * bf2f((ushort_t)vn[j]));
    cv[j] = (1.f - zg) * ng + zg * bf2f((ushort_t)vh[j]);
    ps += cv[j];
  }
  float mean = wsum64(ps) * (1.0f / NG);
  float pq = 0.f;
#pragma unroll
  for (int j = 0; j < 8; j++) { float d = cv[j] - mean; pq += d * d; }
  float rstd = rsqrtf(wsum64(pq) * (1.0f / NG) + 1e-5f);
  float4 g0 = *(const float4*)&lng[f], g1 = *(const float4*)&lng[f + 4];
  float4 b0 = *(const float4*)&lnb[f], b1 = *(const float4*)&lnb[f + 4];
  float gg[8] = {g0.x, g0.y, g0.z, g0.w, g1.x, g1.y, g1.z, g1.w};
  float bbv[8] = {b0.x, b0.y, b0.z, b0.w, b1.x, b1.y, b1.z, b1.w};
  bf16x8 xo;
#pragma unroll
  for (int j = 0; j < 8; j++) xo[j] = (short)f2bf((cv[j] - mean) * rstd * gg[j] + bbv[j]);
  *(bf16x8*)&X0[(size_t)ltok * NG + f] = xo;
}

// ---------- final LN + score (wave per token) ----------
__global__ __launch_bounds__(256) void ln_score_kernel(
    const ushort_t* __restrict__ X, const float* __restrict__ lng,
    const float* __restrict__ lnb, const float* __restrict__ Wsc,
    const float* __restrict__ bsc, float* __restrict__ scores) {
  const int t = threadIdx.x;
  const int lane = t & 63, wv = t >> 6;
  const int ltok = blockIdx.x * 4 + wv;
  const int f = lane * 8;
  bf16x8 xx = *(const bf16x8*)&X[(size_t)ltok * ND + f];
  float x[8];
  float ps = 0.f;
#pragma unroll
  for (int j = 0; j < 8; j++) { x[j] = bf2f((ushort_t)xx[j]); ps += x[j]; }
  float mean = wsum64(ps) * (1.0f / ND);
  float pq = 0.f;
#pragma unroll
  for (int j = 0; j < 8; j++) { float d = x[j] - mean; pq += d * d; }
  float rstd = rsqrtf(wsum64(pq) * (1.0f / ND) + 1e-5f);
  float4 g0 = *(const float4*)&lng[f], g1 = *(const float4*)&lng[f + 4];
  float4 b0 = *(const float4*)&lnb[f], b1 = *(const float4*)&lnb[f + 4];
  float4 w0 = *(const float4*)&Wsc[f], w1 = *(const float4*)&Wsc[f + 4];
  float gg[8] = {g0.x, g0.y, g0.z, g0.w, g1.x, g1.y, g1.z, g1.w};
  float bbv[8] = {b0.x, b0.y, b0.z, b0.w, b1.x, b1.y, b1.z, b1.w};
  float ww[8] = {w0.x, w0.y, w0.z, w0.w, w1.x, w1.y, w1.z, w1.w};
  float d = 0.f;
#pragma unroll
  for (int j = 0; j < 8; j++) d += ((x[j] - mean) * rstd * gg[j] + bbv[j]) * ww[j];
  float dot = wsum64(d);
  if (lane == 0) scores[ltok] = dot + bsc[0];
}

// ---------- fused softmax + LDS-spectrum scatter (one block per batch) ----------
__global__ __launch_bounds__(256) void softmax_scatter_kernel(
    const float* __restrict__ scores, const int* __restrict__ pidx,
    const float* __restrict__ pint, float* __restrict__ spect,
    float* __restrict__ probs) {
  const int b = blockIdx.x;
  const int t = threadIdx.x;
  __shared__ float s_red[4];
  __shared__ float s_spec[NBINS];
  const float* sc = scores + (size_t)b * NS;
  float v[4];
  float mx = -1e30f;
#pragma unroll
  for (int i = 0; i < 4; i++) { v[i] = sc[t + i * 256]; mx = fmaxf(mx, v[i]); }
#pragma unroll
  for (int off = 32; off > 0; off >>= 1) mx = fmaxf(mx, __shfl_down(mx, off));
  if ((t & 63) == 0) s_red[t >> 6] = mx;
  __syncthreads();
  mx = fmaxf(fmaxf(s_red[0], s_red[1]), fmaxf(s_red[2], s_red[3]));
  float e[4], sum = 0.f;
#pragma unroll
  for (int i = 0; i < 4; i++) { e[i] = expf(v[i] - mx); sum += e[i]; }
#pragma unroll
  for (int off = 32; off > 0; off >>= 1) sum += __shfl_down(sum, off);
  __syncthreads();
  if ((t & 63) == 0) s_red[t >> 6] = sum;
  __syncthreads();
  sum = s_red[0] + s_red[1] + s_red[2] + s_red[3];
  float inv = 1.f / sum;
  s_spec[t] = 0.f; s_spec[t + 256] = 0.f;
  float p[4];
#pragma unroll
  for (int i = 0; i < 4; i++) {
    p[i] = e[i] * inv;
    probs[(size_t)b * NS + t + i * 256] = p[i];
  }
  __syncthreads();
#pragma unroll
  for (int i = 0; i < 4; i++) {
    const int s = t + i * 256;
    const int* idx = pidx + ((size_t)b * NS + s) * NM;
    const float* wt = pint + ((size_t)b * NS + s) * NM;
#pragma unroll
    for (int m = 0; m < NM; m++)
      atomicAdd(&s_spec[idx[m]], wt[m] * p[i]);
  }
  __syncthreads();
  spect[(size_t)b * NBINS + t] = s_spec[t];
  spect[(size_t)b * NBINS + t + 256] = s_spec[t + 256];
}

extern "C" void kernel_launch(void* const* d_in, const int* in_sizes, int n_in,
                              void* d_out, int out_size, void* d_ws, size_t ws_size,
                              hipStream_t stream) {
  const float* vert = (const float*)d_in[0];
  const float* mask = (const float*)d_in[1];
  const float* eloh = (const float*)d_in[2];
  const int* subs = (const int*)d_in[3];
  const int* pidx = (const int*)d_in[4];
  const float* pint = (const float*)d_in[5];
  const float* ln_sub_g = (const float*)d_in[6];
  const float* ln_sub_b = (const float*)d_in[7];
  const float* W_ih = (const float*)d_in[8];
  const float* W_hh = (const float*)d_in[9];
  const float* b_ih = (const float*)d_in[10];
  const float* b_hh = (const float*)d_in[11];
  const float* ln_post_g = (const float*)d_in[12];
  const float* ln_post_b = (const float*)d_in[13];
  const float* W1 = (const float*)d_in[14];
  const float* b1 = (const float*)d_in[15];
  const float* W2a = (const float*)d_in[16];
  const float* b2a = (const float*)d_in[17];
  const float* W2b = (const float*)d_in[18];
  const float* b2b = (const float*)d_in[19];
  const float* ln_pre_g = (const float*)d_in[20];
  const float* ln_pre_b = (const float*)d_in[21];
  const float* W_s = (const float*)d_in[22];
  const float* b_s = (const float*)d_in[23];

  float* out = (float*)d_out;            // [0,8192) spect, [8192,24576) probs
  float* probs = out + NB * NBINS;

  // ---- fixed region ----
  char* ws = (char*)d_ws;
  float* scores = (float*)ws;                       // 64 KB
  ushort_t* Whh_bf = (ushort_t*)(ws + 65536);       // 1536*512*2 = 1572864
  ushort_t* W1_bf  = (ushort_t*)(ws + 1638400);     // 512*512*2 = 524288
  ushort_t* W2a_bf = (ushort_t*)(ws + 2162688);
  ushort_t* W2b_bf = (ushort_t*)(ws + 2686976);
  ushort_t* VmT    = (ushort_t*)(ws + 3211264);     // 16*512*32*2 = 524288
  ushort_t* S_bf   = (ushort_t*)(ws + 3735552);     // 16384*32*2 = 1048576
  float*    tcd    = (float*)(ws + 4784128);        // 16384*8*4 = 524288
  float*    PS     = (float*)(ws + 5308416);        // 5*21*1536*4 = 645120
  const size_t fixed = 5953536;

  // ---- chunked region; per-token bytes: SWV 2048 | Hb 1024 | Gh 3072 | X0 1024 = 7168
  const size_t per_tok = 7168;
  int T = NTOK;
  while (T > 1024 && fixed + (size_t)T * per_tok > ws_size) T >>= 1;
  const int nchunks = NTOK / T;

  char* cb = ws + fixed;
  float*    SWV = (float*)cb;                             cb += (size_t)T * 2048;
  ushort_t* Hb  = (ushort_t*)cb;                          cb += (size_t)T * 1024;
  ushort_t* Gh  = (ushort_t*)cb;                          cb += (size_t)T * 3072;
  ushort_t* X0  = (ushort_t*)cb;
  ushort_t* X1  = Gh;                  // Gh dead after gate_ln
  ushort_t* X2  = Gh + (size_t)T * 512;
  ushort_t* X3  = X0;                  // X0 dead after W1 GEMM

  // fused setup: invcnt + PS prefix table + 4 weight cvts + VmT prep + S_bf cvt
  const int setup_items = NTOK + NE * 1536 + 1536 * NG + ND * NG + 2 * ND * ND
                        + NB * NG * NA + NTOK * NA;
  setup_kernel<<<(setup_items + 255) / 256, 256, 0, stream>>>(
      vert, mask, eloh, subs, W_ih, W_hh, W1, W2a, W2b,
      tcd, PS, Whh_bf, W1_bf, W2a_bf, W2b_bf, VmT, S_bf);

  for (int c = 0; c < nchunks; c++) {
    const int tok0 = c * T;

    dim3 gp(T / 128, NG / 128);
    pool_gemm<<<gp, 256, 0, stream>>>(S_bf, VmT, tcd, SWV, tok0);
    finish_kernel<<<T / 4, 256, 0, stream>>>(SWV, ln_sub_g, ln_sub_b, Hb);

    dim3 g1(T / 128, 1536 / 128);
    gemm_bf16<<<g1, 256, 0, stream>>>(Hb, Whh_bf, b_hh, Gh, NG, 1536, 3);

    gate_ln_kernel<<<T / 4, 256, 0, stream>>>(Gh, Hb, tcd + (size_t)tok0 * 8, PS,
                                              b_ih, ln_post_g, ln_post_b, X0);

    dim3 g2(T / 128, ND / 128);
    gemm_bf16<<<g2, 256, 0, stream>>>(X0, W1_bf, b1, X1, NG, ND, 1);
    gemm_bf16<<<g2, 256, 0, stream>>>(X1, W2a_bf, b2a, X2, ND, ND, 1);
    gemm_bf16<<<g2, 256, 0, stream>>>(X2, W2b_bf, b2b, X3, ND, ND, 1);

    ln_score_kernel<<<T / 4, 256, 0, stream>>>(X3, ln_pre_g, ln_pre_b, W_s, b_s,
                                               scores + tok0);
  }

  softmax_scatter_kernel<<<NB, 256, 0, stream>>>(scores, pidx, pint, out, probs);
}